// Round 1
// baseline (764.582 us; speedup 1.0000x reference)
//
#include <hip/hip_runtime.h>
#include <hip/hip_bf16.h>
#include <stdint.h>

typedef unsigned short u16;
typedef __bf16 bf16x8 __attribute__((ext_vector_type(8)));
typedef float f32x4 __attribute__((ext_vector_type(4)));

#define FEAT 512
#define BATCH 8192
#define NC1 20
#define NC2 100
#define NC3 500
#define NC4 2000
#define NC5 10000
#define NCAT 2620   // 20+100+500+2000
#define NTOT 12620

__device__ inline u16 f2bf(float f) {
    unsigned int u = __builtin_bit_cast(unsigned int, f);
    unsigned int r = (u + 0x7FFFu + ((u >> 16) & 1u)) >> 16;
    return (u16)r;
}

__device__ inline float waveReduceSum(float v) {
    #pragma unroll
    for (int off = 32; off > 0; off >>= 1) v += __shfl_xor(v, off);
    return v;
}
__device__ inline float waveReduceMax(float v) {
    #pragma unroll
    for (int off = 32; off > 0; off >>= 1) v = fmaxf(v, __shfl_xor(v, off));
    return v;
}
// 256-thread blocks only
__device__ inline float blockReduceSum(float v, float* sh) {
    int t = threadIdx.x;
    v = waveReduceSum(v);
    __syncthreads();
    if ((t & 63) == 0) sh[t >> 6] = v;
    __syncthreads();
    return sh[0] + sh[1] + sh[2] + sh[3];
}
__device__ inline float blockReduceMax(float v, float* sh) {
    int t = threadIdx.x;
    v = waveReduceMax(v);
    __syncthreads();
    if ((t & 63) == 0) sh[t >> 6] = v;
    __syncthreads();
    return fmaxf(fmaxf(sh[0], sh[1]), fmaxf(sh[2], sh[3]));
}

// ---------------- prep kernels ----------------

__global__ __launch_bounds__(256) void cast_x(const float* __restrict__ x, u16* __restrict__ xb, int n8) {
    int i = blockIdx.x * blockDim.x + threadIdx.x;
    if (i >= n8) return;
    const float* p = x + (size_t)i * 8;
    union { u16 u[8]; uint4 v; } o;
    #pragma unroll
    for (int j = 0; j < 8; ++j) o.u[j] = f2bf(p[j]);
    ((uint4*)xb)[i] = o.v;
}

// one wave per row: l2-normalize row, emit bf16 row + copy bias
__global__ __launch_bounds__(64) void wnorm(const float* __restrict__ W, const float* __restrict__ b,
                                            u16* __restrict__ wb, float* __restrict__ bias, int rows) {
    int r = blockIdx.x; if (r >= rows) return;
    int t = threadIdx.x;
    const float* p = W + (size_t)r * FEAT + t * 8;
    float v[8]; float ss = 0.f;
    #pragma unroll
    for (int j = 0; j < 8; ++j) { v[j] = p[j]; ss += v[j] * v[j]; }
    ss = waveReduceSum(ss);
    float inv = 1.0f / fmaxf(sqrtf(ss), 1e-12f);
    union { u16 u[8]; uint4 q; } o;
    #pragma unroll
    for (int j = 0; j < 8; ++j) o.u[j] = f2bf(v[j] * inv);
    ((uint4*)(wb + (size_t)r * FEAT))[t] = o.q;
    if (t == 0) bias[r] = b[r];
}

// ---------------- GEMM: C[M,N] = Xbf16[M,512] @ Wbf16[N,512]^T + bias ----------------
// 128x128 tile, BK=64, 4 waves (2x2), each wave 64x64 via 4x4 frags of 16x16x32 MFMA.

#define BM 128
#define BN 128
#define BK 64

__global__ __launch_bounds__(256) void gemm_bt(const u16* __restrict__ A, const u16* __restrict__ Bw,
                                               const float* __restrict__ bias, float* __restrict__ C,
                                               int N, int ldc) {
    __shared__ u16 sA[BM * BK];
    __shared__ u16 sB[BN * BK];
    const int t = threadIdx.x;
    const int lane = t & 63, w = t >> 6;
    const int wr = w >> 1, wc = w & 1;
    const int r0 = blockIdx.x * BM, c0 = blockIdx.y * BN;

    f32x4 acc[4][4];
    #pragma unroll
    for (int m = 0; m < 4; ++m)
        #pragma unroll
        for (int n = 0; n < 4; ++n) acc[m][n] = f32x4{0.f, 0.f, 0.f, 0.f};

    for (int kt = 0; kt < FEAT; kt += BK) {
        #pragma unroll
        for (int i = 0; i < 4; ++i) {
            int chunk = i * 256 + t;          // 0..1023, 8 bf16 each
            int row = chunk >> 3, cc = chunk & 7;
            const uint4 va = *reinterpret_cast<const uint4*>(&A[(size_t)(r0 + row) * FEAT + kt + cc * 8]);
            *reinterpret_cast<uint4*>(&sA[row * BK + cc * 8]) = va;
            int brow = c0 + row; if (brow >= N) brow = N - 1;   // clamp; masked at store
            const uint4 vb = *reinterpret_cast<const uint4*>(&Bw[(size_t)brow * FEAT + kt + cc * 8]);
            *reinterpret_cast<uint4*>(&sB[row * BK + cc * 8]) = vb;
        }
        __syncthreads();
        #pragma unroll
        for (int ks = 0; ks < 2; ++ks) {
            const int kk = ks * 32 + (lane >> 4) * 8;
            bf16x8 af[4], bf[4];
            #pragma unroll
            for (int m = 0; m < 4; ++m)
                af[m] = *reinterpret_cast<const bf16x8*>(&sA[(wr * 64 + m * 16 + (lane & 15)) * BK + kk]);
            #pragma unroll
            for (int n = 0; n < 4; ++n)
                bf[n] = *reinterpret_cast<const bf16x8*>(&sB[(wc * 64 + n * 16 + (lane & 15)) * BK + kk]);
            #pragma unroll
            for (int m = 0; m < 4; ++m)
                #pragma unroll
                for (int n = 0; n < 4; ++n)
                    acc[m][n] = __builtin_amdgcn_mfma_f32_16x16x32_bf16(af[m], bf[n], acc[m][n], 0, 0, 0);
        }
        __syncthreads();
    }
    // C/D layout: col = lane&15, row = (lane>>4)*4 + j   [measured m89/m91]
    #pragma unroll
    for (int m = 0; m < 4; ++m) {
        #pragma unroll
        for (int n = 0; n < 4; ++n) {
            int col = c0 + wc * 64 + n * 16 + (lane & 15);
            if (col < N) {
                float bv = bias[col];
                int rbase = r0 + wr * 64 + m * 16 + (lane >> 4) * 4;
                #pragma unroll
                for (int j = 0; j < 4; ++j)
                    C[(size_t)(rbase + j) * ldc + col] = acc[m][n][j] + bv;
            }
        }
    }
}

// ---------------- softmax / CE / JSD ----------------

__global__ __launch_bounds__(256) void rowstat(const float* __restrict__ l5, float* __restrict__ mrow,
                                               float* __restrict__ srow) {
    __shared__ float sh[4];
    int b = blockIdx.x;
    const float* row = l5 + (size_t)b * NC5;
    float m = -1e30f;
    for (int c = threadIdx.x; c < NC5; c += 256) m = fmaxf(m, row[c]);
    m = blockReduceMax(m, sh);
    float s = 0.f;
    for (int c = threadIdx.x; c < NC5; c += 256) s += __expf(row[c] - m);
    s = blockReduceSum(s, sh);
    if (threadIdx.x == 0) { mrow[b] = m; srow[b] = s; }
}

__global__ __launch_bounds__(256) void ce_kernel(const float* __restrict__ l5, const int* __restrict__ tgt,
                                                 const float* __restrict__ mrow, const float* __restrict__ srow,
                                                 float* __restrict__ ce) {
    int b = blockIdx.x * blockDim.x + threadIdx.x;
    if (b >= BATCH) return;
    int tg = tgt[b];
    ce[b] = -(l5[(size_t)b * NC5 + tg] - mrow[b] - logf(srow[b]));
}

__global__ __launch_bounds__(256) void softmax_rows(float* __restrict__ pcat, int off, int C) {
    __shared__ float sh[4];
    int b = blockIdx.x;
    float* row = pcat + (size_t)b * NCAT + off;
    float m = -1e30f;
    for (int c = threadIdx.x; c < C; c += 256) m = fmaxf(m, row[c]);
    m = blockReduceMax(m, sh);
    float s = 0.f;
    for (int c = threadIdx.x; c < C; c += 256) s += __expf(row[c] - m);
    s = blockReduceSum(s, sh);
    float inv = 1.0f / s;
    for (int c = threadIdx.x; c < C; c += 256) row[c] = __expf(row[c] - m) * inv;
}

// fused: l5 -> p5 (written to d_out), group-of-5 col aggregation, JSD(aggp5, p4)
__global__ __launch_bounds__(256) void p5_jsd45(const float* __restrict__ pcat, float* __restrict__ out,
                                                const float* __restrict__ mrow, const float* __restrict__ srow,
                                                float* __restrict__ jsdrow) {
    __shared__ float sh[4];
    int b = blockIdx.x;
    float* row = out + (size_t)b * NC5;
    const float* p4 = pcat + (size_t)b * NCAT + 620;
    float m = mrow[b], inv = 1.0f / srow[b];
    float klpm = 0.f, klqm = 0.f;
    for (int g = threadIdx.x; g < NC4; g += 256) {
        float pv[5]; float q = 0.f;
        #pragma unroll
        for (int f = 0; f < 5; ++f) { float p = __expf(row[g * 5 + f] - m) * inv; pv[f] = p; q += p; }
        #pragma unroll
        for (int f = 0; f < 5; ++f) row[g * 5 + f] = pv[f];
        float pp = p4[g];
        float mm = 0.5f * (q + pp);
        float lm = __logf(mm + 1e-8f);
        klpm += q * (__logf(q + 1e-8f) - lm);
        klqm += pp * (__logf(pp + 1e-8f) - lm);
    }
    float tot = blockReduceSum(0.5f * (klpm + klqm), sh);
    if (threadIdx.x == 0) jsdrow[b] = tot;
}

__global__ __launch_bounds__(256) void jsd_pair(const float* __restrict__ pcat, int childOff, int parentOff,
                                                int fan, int nPar, float* __restrict__ jsdrow) {
    __shared__ float sh[4];
    int b = blockIdx.x;
    const float* ch = pcat + (size_t)b * NCAT + childOff;
    const float* pa = pcat + (size_t)b * NCAT + parentOff;
    float klpm = 0.f, klqm = 0.f;
    for (int g = threadIdx.x; g < nPar; g += 256) {
        float q = 0.f;
        for (int f = 0; f < fan; ++f) q += ch[g * fan + f];
        float pp = pa[g];
        float mm = 0.5f * (q + pp);
        float lm = __logf(mm + 1e-8f);
        klpm += q * (__logf(q + 1e-8f) - lm);
        klqm += pp * (__logf(pp + 1e-8f) - lm);
    }
    float tot = blockReduceSum(0.5f * (klpm + klqm), sh);
    if (threadIdx.x == 0) jsdrow[b] = tot;
}

// one wave per parent row: cos(parent_norm_row, l2norm(sum of child_norm_rows))
__global__ __launch_bounds__(64) void wcos(const float* __restrict__ Wp, const float* __restrict__ Wc,
                                           int fan, float* __restrict__ outBuf) {
    int j = blockIdx.x; int t = threadIdx.x;
    float hat[8] = {0, 0, 0, 0, 0, 0, 0, 0};
    for (int c = 0; c < fan; ++c) {
        const float* cr = Wc + ((size_t)(j * fan + c)) * FEAT + t * 8;
        float v[8]; float ss = 0.f;
        #pragma unroll
        for (int i = 0; i < 8; ++i) { v[i] = cr[i]; ss += v[i] * v[i]; }
        ss = waveReduceSum(ss);
        float inv = 1.0f / fmaxf(sqrtf(ss), 1e-12f);
        #pragma unroll
        for (int i = 0; i < 8; ++i) hat[i] += v[i] * inv;
    }
    float hs = 0.f;
    #pragma unroll
    for (int i = 0; i < 8; ++i) hs += hat[i] * hat[i];
    hs = waveReduceSum(hs);
    float hinv = 1.0f / fmaxf(sqrtf(hs), 1e-12f);
    const float* pr = Wp + (size_t)j * FEAT + t * 8;
    float ps = 0.f, dot = 0.f;
    #pragma unroll
    for (int i = 0; i < 8; ++i) { float pv = pr[i]; ps += pv * pv; dot += pv * hat[i]; }
    ps = waveReduceSum(ps);
    dot = waveReduceSum(dot);
    if (t == 0) outBuf[j] = dot * hinv / fmaxf(sqrtf(ps), 1e-12f);
}

__global__ __launch_bounds__(256) void finalize(const float* __restrict__ ce, const float* __restrict__ j45,
                                                const float* __restrict__ j34, const float* __restrict__ j23,
                                                const float* __restrict__ j12, const float* __restrict__ c45,
                                                const float* __restrict__ c34, const float* __restrict__ c23,
                                                const float* __restrict__ c12, float* __restrict__ lossOut) {
    __shared__ float sh[4];
    auto meanArr = [&](const float* a, int n) {
        float s = 0.f;
        for (int i = threadIdx.x; i < n; i += 256) s += a[i];
        s = blockReduceSum(s, sh);
        return s / n;
    };
    float loss = meanArr(ce, BATCH);
    loss += meanArr(j45, BATCH) + meanArr(j34, BATCH) + meanArr(j23, BATCH) + meanArr(j12, BATCH);
    loss -= meanArr(c45, NC4) + meanArr(c34, NC3) + meanArr(c23, NC2) + meanArr(c12, NC1);
    if (threadIdx.x == 0) *lossOut = loss;
}

// ---------------- launch ----------------

extern "C" void kernel_launch(void* const* d_in, const int* in_sizes, int n_in,
                              void* d_out, int out_size, void* d_ws, size_t ws_size,
                              hipStream_t stream) {
    const float* x  = (const float*)d_in[0];
    const int*   tg = (const int*)d_in[1];
    const float* W1 = (const float*)d_in[2];  const float* b1 = (const float*)d_in[3];
    const float* W2 = (const float*)d_in[4];  const float* b2 = (const float*)d_in[5];
    const float* W3 = (const float*)d_in[6];  const float* b3 = (const float*)d_in[7];
    const float* W4 = (const float*)d_in[8];  const float* b4 = (const float*)d_in[9];
    const float* W5 = (const float*)d_in[10]; const float* b5 = (const float*)d_in[11];
    float* out = (float*)d_out;

    char* ws = (char*)d_ws;
    size_t off = 0;
    auto alloc = [&](size_t bytes) { void* p = ws + off; off = (off + bytes + 255) & ~(size_t)255; return p; };
    u16*   xb      = (u16*)alloc((size_t)BATCH * FEAT * 2);
    u16*   wb      = (u16*)alloc((size_t)NTOT * FEAT * 2);
    float* biascat = (float*)alloc((size_t)NTOT * 4);
    float* pcat    = (float*)alloc((size_t)BATCH * NCAT * 4);
    float* mrow    = (float*)alloc((size_t)BATCH * 4);
    float* srow    = (float*)alloc((size_t)BATCH * 4);
    float* cerow   = (float*)alloc((size_t)BATCH * 4);
    float* j45     = (float*)alloc((size_t)BATCH * 4);
    float* j34     = (float*)alloc((size_t)BATCH * 4);
    float* j23     = (float*)alloc((size_t)BATCH * 4);
    float* j12     = (float*)alloc((size_t)BATCH * 4);
    float* c45     = (float*)alloc((size_t)NC4 * 4);
    float* c34     = (float*)alloc((size_t)NC3 * 4);
    float* c23     = (float*)alloc((size_t)NC2 * 4);
    float* c12     = (float*)alloc((size_t)NC1 * 4);

    cast_x<<<(BATCH * FEAT / 8 + 255) / 256, 256, 0, stream>>>(x, xb, BATCH * FEAT / 8);
    wnorm<<<NC1, 64, 0, stream>>>(W1, b1, wb + (size_t)0    * FEAT, biascat + 0,    NC1);
    wnorm<<<NC2, 64, 0, stream>>>(W2, b2, wb + (size_t)20   * FEAT, biascat + 20,   NC2);
    wnorm<<<NC3, 64, 0, stream>>>(W3, b3, wb + (size_t)120  * FEAT, biascat + 120,  NC3);
    wnorm<<<NC4, 64, 0, stream>>>(W4, b4, wb + (size_t)620  * FEAT, biascat + 620,  NC4);
    wnorm<<<NC5, 64, 0, stream>>>(W5, b5, wb + (size_t)2620 * FEAT, biascat + 2620, NC5);

    gemm_bt<<<dim3(BATCH / BM, (NCAT + BN - 1) / BN), 256, 0, stream>>>(xb, wb, biascat, pcat, NCAT, NCAT);
    gemm_bt<<<dim3(BATCH / BM, (NC5 + BN - 1) / BN), 256, 0, stream>>>(xb, wb + (size_t)2620 * FEAT,
                                                                       biascat + 2620, out, NC5, NC5);

    rowstat<<<BATCH, 256, 0, stream>>>(out, mrow, srow);
    ce_kernel<<<(BATCH + 255) / 256, 256, 0, stream>>>(out, tg, mrow, srow, cerow);

    softmax_rows<<<BATCH, 256, 0, stream>>>(pcat, 0, NC1);
    softmax_rows<<<BATCH, 256, 0, stream>>>(pcat, 20, NC2);
    softmax_rows<<<BATCH, 256, 0, stream>>>(pcat, 120, NC3);
    softmax_rows<<<BATCH, 256, 0, stream>>>(pcat, 620, NC4);

    p5_jsd45<<<BATCH, 256, 0, stream>>>(pcat, out, mrow, srow, j45);
    jsd_pair<<<BATCH, 256, 0, stream>>>(pcat, 620, 120, 4, NC3, j34);
    jsd_pair<<<BATCH, 256, 0, stream>>>(pcat, 120, 20, 5, NC2, j23);
    jsd_pair<<<BATCH, 256, 0, stream>>>(pcat, 20, 0, 5, NC1, j12);

    wcos<<<NC4, 64, 0, stream>>>(W4, W5, 5, c45);
    wcos<<<NC3, 64, 0, stream>>>(W3, W4, 4, c34);
    wcos<<<NC2, 64, 0, stream>>>(W2, W3, 5, c23);
    wcos<<<NC1, 64, 0, stream>>>(W1, W2, 5, c12);

    finalize<<<1, 256, 0, stream>>>(cerow, j45, j34, j23, j12, c45, c34, c23, c12,
                                    out + (size_t)BATCH * NC5);
}

// Round 2
// 553.976 us; speedup vs baseline: 1.3802x; 1.3802x over previous
//
#include <hip/hip_runtime.h>
#include <hip/hip_bf16.h>
#include <stdint.h>

typedef unsigned short u16;
typedef __bf16 bf16x8 __attribute__((ext_vector_type(8)));
typedef float f32x4 __attribute__((ext_vector_type(4)));

#define FEAT 512
#define BATCH 8192
#define NC1 20
#define NC2 100
#define NC3 500
#define NC4 2000
#define NC5 10000
#define NCAT 2620
#define NTOT 12620

__device__ inline u16 f2bf(float f) {
    unsigned int u = __builtin_bit_cast(unsigned int, f);
    unsigned int r = (u + 0x7FFFu + ((u >> 16) & 1u)) >> 16;
    return (u16)r;
}
__device__ inline float bfu(u16 u) {
    return __builtin_bit_cast(float, (unsigned int)u << 16);
}

__device__ inline float waveReduceSum(float v) {
    #pragma unroll
    for (int off = 32; off > 0; off >>= 1) v += __shfl_xor(v, off);
    return v;
}
__device__ inline float waveReduceMax(float v) {
    #pragma unroll
    for (int off = 32; off > 0; off >>= 1) v = fmaxf(v, __shfl_xor(v, off));
    return v;
}
__device__ inline float blockReduceSum(float v, float* sh) {
    int t = threadIdx.x;
    v = waveReduceSum(v);
    __syncthreads();
    if ((t & 63) == 0) sh[t >> 6] = v;
    __syncthreads();
    return sh[0] + sh[1] + sh[2] + sh[3];
}
__device__ inline float blockReduceMax(float v, float* sh) {
    int t = threadIdx.x;
    v = waveReduceMax(v);
    __syncthreads();
    if ((t & 63) == 0) sh[t >> 6] = v;
    __syncthreads();
    return fmaxf(fmaxf(sh[0], sh[1]), fmaxf(sh[2], sh[3]));
}

__device__ inline void gload16(const void* g, void* l) {
    __builtin_amdgcn_global_load_lds((const __attribute__((address_space(1))) void*)g,
                                     (__attribute__((address_space(3))) void*)l, 16, 0, 0);
}

// ---------------- prep kernels ----------------

__global__ __launch_bounds__(256) void cast_x(const float* __restrict__ x, u16* __restrict__ xb, int n8) {
    int i = blockIdx.x * blockDim.x + threadIdx.x;
    if (i >= n8) return;
    const float* p = x + (size_t)i * 8;
    union { u16 u[8]; uint4 v; } o;
    #pragma unroll
    for (int j = 0; j < 8; ++j) o.u[j] = f2bf(p[j]);
    ((uint4*)xb)[i] = o.v;
}

// one wave per row across ALL levels: l2-normalize, emit bf16 + bias
__global__ __launch_bounds__(64) void wnorm_all(const float* __restrict__ W1, const float* __restrict__ b1,
                                                const float* __restrict__ W2, const float* __restrict__ b2,
                                                const float* __restrict__ W3, const float* __restrict__ b3,
                                                const float* __restrict__ W4, const float* __restrict__ b4,
                                                const float* __restrict__ W5, const float* __restrict__ b5,
                                                u16* __restrict__ wb, float* __restrict__ biascat) {
    int r = blockIdx.x;
    const float* W; const float* b; int lr;
    if      (r < 20)   { W = W1; b = b1; lr = r; }
    else if (r < 120)  { W = W2; b = b2; lr = r - 20; }
    else if (r < 620)  { W = W3; b = b3; lr = r - 120; }
    else if (r < 2620) { W = W4; b = b4; lr = r - 620; }
    else               { W = W5; b = b5; lr = r - 2620; }
    int t = threadIdx.x;
    const float* p = W + (size_t)lr * FEAT + t * 8;
    float v[8]; float ss = 0.f;
    #pragma unroll
    for (int j = 0; j < 8; ++j) { v[j] = p[j]; ss += v[j] * v[j]; }
    ss = waveReduceSum(ss);
    float inv = 1.0f / fmaxf(sqrtf(ss), 1e-12f);
    union { u16 u[8]; uint4 q; } o;
    #pragma unroll
    for (int j = 0; j < 8; ++j) o.u[j] = f2bf(v[j] * inv);
    ((uint4*)(wb + (size_t)r * FEAT))[t] = o.q;
    if (t == 0) biascat[r] = b[lr];
}

// ---------------- GEMM ----------------
// 128x128x64 tile, 4 waves 2x2, global_load_lds w16 staging, XOR-swizzled LDS.
// STATS: also emit per-(row, coltile) softmax partials (max, sumexp).

#define BM 128
#define BN 128
#define BK 64

template <bool STATS>
__global__ __launch_bounds__(256) void gemm_bt(const u16* __restrict__ A, const u16* __restrict__ Bw,
                                               const float* __restrict__ bias, float* __restrict__ C,
                                               int N, int ldc,
                                               float* __restrict__ pmax, float* __restrict__ psum, int nct) {
    __shared__ u16 sAB[2 * BM * BK];           // 32 KB: sA then sB
    char* sAb = (char*)sAB;
    char* sBb = (char*)(sAB + BM * BK);
    const int t = threadIdx.x;
    const int lane = t & 63, w = t >> 6;
    const int lane15 = lane & 15, q = lane >> 4;
    const int wr = w >> 1, wc = w & 1;
    const int r0 = blockIdx.x * BM, c0 = blockIdx.y * BN;

    f32x4 acc[4][4];
    #pragma unroll
    for (int m = 0; m < 4; ++m)
        #pragma unroll
        for (int n = 0; n < 4; ++n) acc[m][n] = f32x4{0.f, 0.f, 0.f, 0.f};

    for (int kt = 0; kt < FEAT; kt += BK) {
        // stage: 1024 chunks of 16B per tile (A then B); per wave-issue: 64 lanes x 16B
        #pragma unroll
        for (int i = 0; i < 4; ++i) {
            int chunk = (i * 4 + w) * 64 + lane;    // 0..1023
            int row = chunk >> 3, blk = chunk & 7;  // 8x16B blocks per row
            int srck = 8 * (blk ^ (row & 7));       // swizzled source k (bf16 idx)
            const u16* ga = A + (size_t)(r0 + row) * FEAT + kt + srck;
            gload16(ga, sAb + (size_t)(i * 4 + w) * 1024);
            int brow = c0 + row; if (brow >= N) brow = N - 1;
            const u16* gb = Bw + (size_t)brow * FEAT + kt + srck;
            gload16(gb, sBb + (size_t)(i * 4 + w) * 1024);
        }
        __syncthreads();
        #pragma unroll
        for (int ks = 0; ks < 2; ++ks) {
            const int kko = ks * 4 + q;             // 16B-block index along k
            bf16x8 af[4], bv[4];
            #pragma unroll
            for (int m = 0; m < 4; ++m) {
                int row = wr * 64 + m * 16 + lane15;
                af[m] = *reinterpret_cast<const bf16x8*>(sAb + row * 128 + 16 * (kko ^ (row & 7)));
            }
            #pragma unroll
            for (int n = 0; n < 4; ++n) {
                int row = wc * 64 + n * 16 + lane15;
                bv[n] = *reinterpret_cast<const bf16x8*>(sBb + row * 128 + 16 * (kko ^ (row & 7)));
            }
            #pragma unroll
            for (int m = 0; m < 4; ++m)
                #pragma unroll
                for (int n = 0; n < 4; ++n)
                    acc[m][n] = __builtin_amdgcn_mfma_f32_16x16x32_bf16(af[m], bv[n], acc[m][n], 0, 0, 0);
        }
        __syncthreads();
    }

    // bias add (in place into acc)
    bool cval[4];
    #pragma unroll
    for (int n = 0; n < 4; ++n) {
        int col = c0 + wc * 64 + n * 16 + lane15;
        cval[n] = (col < N);
        float bvv = bias[cval[n] ? col : (N - 1)];
        #pragma unroll
        for (int m = 0; m < 4; ++m)
            #pragma unroll
            for (int j = 0; j < 4; ++j) acc[m][n][j] += bvv;
    }

    if (STATS) {
        float* fsh = (float*)sAB;   // reuse LDS: [0..255] maxes, [256..511] sums
        float rm[4][4];
        #pragma unroll
        for (int m = 0; m < 4; ++m)
            #pragma unroll
            for (int j = 0; j < 4; ++j) {
                float v = -1e30f;
                #pragma unroll
                for (int n = 0; n < 4; ++n) if (cval[n]) v = fmaxf(v, acc[m][n][j]);
                #pragma unroll
                for (int d = 1; d < 16; d <<= 1) v = fmaxf(v, __shfl_xor(v, d));
                rm[m][j] = v;
            }
        if (lane15 == 0) {
            #pragma unroll
            for (int m = 0; m < 4; ++m)
                #pragma unroll
                for (int j = 0; j < 4; ++j)
                    fsh[wc * 128 + wr * 64 + m * 16 + q * 4 + j] = rm[m][j];
        }
        __syncthreads();
        float bm[4][4];
        #pragma unroll
        for (int m = 0; m < 4; ++m)
            #pragma unroll
            for (int j = 0; j < 4; ++j) {
                int lr = wr * 64 + m * 16 + q * 4 + j;
                bm[m][j] = fmaxf(fsh[lr], fsh[128 + lr]);
            }
        float sm[4][4];
        #pragma unroll
        for (int m = 0; m < 4; ++m)
            #pragma unroll
            for (int j = 0; j < 4; ++j) {
                float s = 0.f;
                #pragma unroll
                for (int n = 0; n < 4; ++n) if (cval[n]) s += __expf(acc[m][n][j] - bm[m][j]);
                #pragma unroll
                for (int d = 1; d < 16; d <<= 1) s += __shfl_xor(s, d);
                sm[m][j] = s;
            }
        if (lane15 == 0) {
            #pragma unroll
            for (int m = 0; m < 4; ++m)
                #pragma unroll
                for (int j = 0; j < 4; ++j)
                    fsh[256 + wc * 128 + wr * 64 + m * 16 + q * 4 + j] = sm[m][j];
        }
        __syncthreads();
        if (wc == 0 && lane15 == 0) {
            #pragma unroll
            for (int m = 0; m < 4; ++m)
                #pragma unroll
                for (int j = 0; j < 4; ++j) {
                    int lr = wr * 64 + m * 16 + q * 4 + j;
                    size_t idx = (size_t)(r0 + lr) * nct + blockIdx.y;
                    pmax[idx] = bm[m][j];
                    psum[idx] = fsh[256 + lr] + fsh[256 + 128 + lr];
                }
        }
    }

    // store f32 (16-lane x 4B = 64B runs)
    #pragma unroll
    for (int m = 0; m < 4; ++m) {
        #pragma unroll
        for (int n = 0; n < 4; ++n) {
            int col = c0 + wc * 64 + n * 16 + lane15;
            if (col < N) {
                int rbase = r0 + wr * 64 + m * 16 + q * 4;
                #pragma unroll
                for (int j = 0; j < 4; ++j)
                    C[(size_t)(rbase + j) * ldc + col] = acc[m][n][j];
            }
        }
    }
}

// ---------------- row-stat merge + CE (wave per row) ----------------

__global__ __launch_bounds__(256) void rowreduce_ce(const float* __restrict__ pmax, const float* __restrict__ psum,
                                                    int nct, const float* __restrict__ l5, const int* __restrict__ tgt,
                                                    float* __restrict__ logsB, float* __restrict__ cerow) {
    int w = threadIdx.x >> 6, lane = threadIdx.x & 63;
    int b = blockIdx.x * 4 + w;
    if (b >= BATCH) return;
    const float* pm = pmax + (size_t)b * nct;
    const float* ps = psum + (size_t)b * nct;
    float gm = -1e30f;
    for (int i = lane; i < nct; i += 64) gm = fmaxf(gm, pm[i]);
    gm = waveReduceMax(gm);
    float s = 0.f;
    for (int i = lane; i < nct; i += 64) s += ps[i] * __expf(pm[i] - gm);
    s = waveReduceSum(s);
    float ls = gm + __logf(s);
    if (lane == 0) {
        logsB[b] = ls;
        int tg = tgt[b];
        cerow[b] = -(l5[(size_t)b * NC5 + tg] - ls);
    }
}

// ---------------- fused probabilities + all JSDs (block per row) ----------------
// p5 = exp(l5 - lse) written IN PLACE into d_out; bf16 copy kept in LDS for the
// fanout-5 aggregation; p1..p4 computed in LDS from pcat row; 4 JSD terms out.

__global__ __launch_bounds__(256) void probs_all(float* __restrict__ out, const float* __restrict__ pcat,
                                                 const float* __restrict__ logsB,
                                                 float* __restrict__ j12, float* __restrict__ j23,
                                                 float* __restrict__ j34, float* __restrict__ j45) {
    __shared__ u16 P5[NC5];
    __shared__ float PC[2624];
    __shared__ float sh[4];
    int b = blockIdx.x, t = threadIdx.x;
    float ls = logsB[b];
    float* orow = out + (size_t)b * NC5;
    const float* prow = pcat + (size_t)b * NCAT;

    for (int c = t; c < NCAT / 4; c += 256) {
        f32x4 v = ((const f32x4*)prow)[c];
        #pragma unroll
        for (int k = 0; k < 4; ++k) PC[c * 4 + k] = v[k];
    }
    for (int c = t; c < NC5 / 4; c += 256) {
        f32x4 v = ((f32x4*)orow)[c];
        f32x4 p;
        #pragma unroll
        for (int k = 0; k < 4; ++k) p[k] = __expf(v[k] - ls);
        ((f32x4*)orow)[c] = p;
        ushort4 pk;
        pk.x = f2bf(p[0]); pk.y = f2bf(p[1]); pk.z = f2bf(p[2]); pk.w = f2bf(p[3]);
        *(ushort4*)&P5[c * 4] = pk;
    }
    __syncthreads();

    // softmax segments in PC: {0,20},{20,100},{120,500},{620,2000}
    auto softmax_seg = [&](int off, int C) {
        float m = -1e30f;
        for (int c = t; c < C; c += 256) m = fmaxf(m, PC[off + c]);
        m = blockReduceMax(m, sh);
        float s = 0.f;
        for (int c = t; c < C; c += 256) { float e = __expf(PC[off + c] - m); PC[off + c] = e; s += e; }
        s = blockReduceSum(s, sh);
        float inv = 1.0f / s;
        for (int c = t; c < C; c += 256) PC[off + c] *= inv;
    };
    softmax_seg(0, NC1);
    softmax_seg(20, NC2);
    softmax_seg(120, NC3);
    softmax_seg(620, NC4);
    __syncthreads();

    // jsd45: agg p5 (fan 5) vs p4
    {
        float klpm = 0.f, klqm = 0.f;
        for (int g = t; g < NC4; g += 256) {
            float qv = 0.f;
            #pragma unroll
            for (int f = 0; f < 5; ++f) qv += bfu(P5[5 * g + f]);
            float pp = PC[620 + g];
            float mm = 0.5f * (qv + pp);
            float lm = __logf(mm + 1e-8f);
            klpm += qv * (__logf(qv + 1e-8f) - lm);
            klqm += pp * (__logf(pp + 1e-8f) - lm);
        }
        float tot = blockReduceSum(0.5f * (klpm + klqm), sh);
        if (t == 0) j45[b] = tot;
    }
    auto jsd_seg = [&](int childOff, int fan, int parentOff, int nPar, float* dst) {
        float klpm = 0.f, klqm = 0.f;
        for (int g = t; g < nPar; g += 256) {
            float qv = 0.f;
            for (int f = 0; f < fan; ++f) qv += PC[childOff + g * fan + f];
            float pp = PC[parentOff + g];
            float mm = 0.5f * (qv + pp);
            float lm = __logf(mm + 1e-8f);
            klpm += qv * (__logf(qv + 1e-8f) - lm);
            klqm += pp * (__logf(pp + 1e-8f) - lm);
        }
        float tot = blockReduceSum(0.5f * (klpm + klqm), sh);
        if (t == 0) dst[b] = tot;
    };
    jsd_seg(620, 4, 120, NC3, j34);
    jsd_seg(120, 5, 20, NC2, j23);
    jsd_seg(20, 5, 0, NC1, j12);
}

// ---------------- weight cosine terms ----------------

__global__ __launch_bounds__(64) void wcos(const float* __restrict__ Wp, const float* __restrict__ Wc,
                                           int fan, float* __restrict__ outBuf) {
    int j = blockIdx.x; int t = threadIdx.x;
    float hat[8] = {0, 0, 0, 0, 0, 0, 0, 0};
    for (int c = 0; c < fan; ++c) {
        const float* cr = Wc + ((size_t)(j * fan + c)) * FEAT + t * 8;
        float v[8]; float ss = 0.f;
        #pragma unroll
        for (int i = 0; i < 8; ++i) { v[i] = cr[i]; ss += v[i] * v[i]; }
        ss = waveReduceSum(ss);
        float inv = 1.0f / fmaxf(sqrtf(ss), 1e-12f);
        #pragma unroll
        for (int i = 0; i < 8; ++i) hat[i] += v[i] * inv;
    }
    float hs = 0.f;
    #pragma unroll
    for (int i = 0; i < 8; ++i) hs += hat[i] * hat[i];
    hs = waveReduceSum(hs);
    float hinv = 1.0f / fmaxf(sqrtf(hs), 1e-12f);
    const float* pr = Wp + (size_t)j * FEAT + t * 8;
    float ps = 0.f, dot = 0.f;
    #pragma unroll
    for (int i = 0; i < 8; ++i) { float pv = pr[i]; ps += pv * pv; dot += pv * hat[i]; }
    ps = waveReduceSum(ps);
    dot = waveReduceSum(dot);
    if (t == 0) outBuf[j] = dot * hinv / fmaxf(sqrtf(ps), 1e-12f);
}

__global__ __launch_bounds__(256) void finalize(const float* __restrict__ ce, const float* __restrict__ j45,
                                                const float* __restrict__ j34, const float* __restrict__ j23,
                                                const float* __restrict__ j12, const float* __restrict__ c45,
                                                const float* __restrict__ c34, const float* __restrict__ c23,
                                                const float* __restrict__ c12, float* __restrict__ lossOut) {
    __shared__ float sh[4];
    auto meanArr = [&](const float* a, int n) {
        float s = 0.f;
        for (int i = threadIdx.x; i < n; i += 256) s += a[i];
        s = blockReduceSum(s, sh);
        return s / n;
    };
    float loss = meanArr(ce, BATCH);
    loss += meanArr(j45, BATCH) + meanArr(j34, BATCH) + meanArr(j23, BATCH) + meanArr(j12, BATCH);
    loss -= meanArr(c45, NC4) + meanArr(c34, NC3) + meanArr(c23, NC2) + meanArr(c12, NC1);
    if (threadIdx.x == 0) *lossOut = loss;
}

// ---------------- launch ----------------

extern "C" void kernel_launch(void* const* d_in, const int* in_sizes, int n_in,
                              void* d_out, int out_size, void* d_ws, size_t ws_size,
                              hipStream_t stream) {
    const float* x  = (const float*)d_in[0];
    const int*   tg = (const int*)d_in[1];
    const float* W1 = (const float*)d_in[2];  const float* b1 = (const float*)d_in[3];
    const float* W2 = (const float*)d_in[4];  const float* b2 = (const float*)d_in[5];
    const float* W3 = (const float*)d_in[6];  const float* b3 = (const float*)d_in[7];
    const float* W4 = (const float*)d_in[8];  const float* b4 = (const float*)d_in[9];
    const float* W5 = (const float*)d_in[10]; const float* b5 = (const float*)d_in[11];
    float* out = (float*)d_out;

    const int NCT = (NC5 + BN - 1) / BN;   // 79 column tiles for l5

    char* ws = (char*)d_ws;
    size_t off = 0;
    auto alloc = [&](size_t bytes) { void* p = ws + off; off = (off + bytes + 255) & ~(size_t)255; return p; };
    u16*   xb      = (u16*)alloc((size_t)BATCH * FEAT * 2);
    u16*   wb      = (u16*)alloc((size_t)NTOT * FEAT * 2);
    float* biascat = (float*)alloc((size_t)NTOT * 4);
    float* pcat    = (float*)alloc((size_t)BATCH * NCAT * 4);
    float* pmax    = (float*)alloc((size_t)BATCH * NCT * 4);
    float* psum    = (float*)alloc((size_t)BATCH * NCT * 4);
    float* logsB   = (float*)alloc((size_t)BATCH * 4);
    float* cerow   = (float*)alloc((size_t)BATCH * 4);
    float* j45     = (float*)alloc((size_t)BATCH * 4);
    float* j34     = (float*)alloc((size_t)BATCH * 4);
    float* j23     = (float*)alloc((size_t)BATCH * 4);
    float* j12     = (float*)alloc((size_t)BATCH * 4);
    float* c45     = (float*)alloc((size_t)NC4 * 4);
    float* c34     = (float*)alloc((size_t)NC3 * 4);
    float* c23     = (float*)alloc((size_t)NC2 * 4);
    float* c12     = (float*)alloc((size_t)NC1 * 4);

    cast_x<<<(BATCH * FEAT / 8 + 255) / 256, 256, 0, stream>>>(x, xb, BATCH * FEAT / 8);
    wnorm_all<<<NTOT, 64, 0, stream>>>(W1, b1, W2, b2, W3, b3, W4, b4, W5, b5, wb, biascat);

    gemm_bt<false><<<dim3(BATCH / BM, (NCAT + BN - 1) / BN), 256, 0, stream>>>(
        xb, wb, biascat, pcat, NCAT, NCAT, nullptr, nullptr, 0);
    gemm_bt<true><<<dim3(BATCH / BM, NCT), 256, 0, stream>>>(
        xb, wb + (size_t)NCAT * FEAT, biascat + NCAT, out, NC5, NC5, pmax, psum, NCT);

    rowreduce_ce<<<BATCH / 4, 256, 0, stream>>>(pmax, psum, NCT, out, tg, logsB, cerow);
    probs_all<<<BATCH, 256, 0, stream>>>(out, pcat, logsB, j12, j23, j34, j45);

    wcos<<<NC4, 64, 0, stream>>>(W4, W5, 5, c45);
    wcos<<<NC3, 64, 0, stream>>>(W3, W4, 4, c34);
    wcos<<<NC2, 64, 0, stream>>>(W2, W3, 5, c23);
    wcos<<<NC1, 64, 0, stream>>>(W1, W2, 5, c12);

    finalize<<<1, 256, 0, stream>>>(cerow, j45, j34, j23, j12, c45, c34, c23, c12,
                                    out + (size_t)BATCH * NC5);
}

// Round 3
// 493.658 us; speedup vs baseline: 1.5488x; 1.1222x over previous
//
#include <hip/hip_runtime.h>
#include <hip/hip_bf16.h>
#include <stdint.h>

typedef unsigned short u16;
typedef __bf16 bf16x8 __attribute__((ext_vector_type(8)));
typedef float f32x4 __attribute__((ext_vector_type(4)));

#define FEAT 512
#define BATCH 8192
#define NC1 20
#define NC2 100
#define NC3 500
#define NC4 2000
#define NC5 10000
#define NCAT 2620
#define LDP 2624          // padded leading dim for pcat (uint4-clean bf16 rows)
#define NTOT 12620

__device__ inline u16 f2bf(float f) {
    unsigned int u = __builtin_bit_cast(unsigned int, f);
    unsigned int r = (u + 0x7FFFu + ((u >> 16) & 1u)) >> 16;
    return (u16)r;
}
__device__ inline float bfu(u16 u) {
    return __builtin_bit_cast(float, (unsigned int)u << 16);
}

__device__ inline float waveReduceSum(float v) {
    #pragma unroll
    for (int off = 32; off > 0; off >>= 1) v += __shfl_xor(v, off);
    return v;
}
__device__ inline float waveReduceMax(float v) {
    #pragma unroll
    for (int off = 32; off > 0; off >>= 1) v = fmaxf(v, __shfl_xor(v, off));
    return v;
}
__device__ inline float blockReduceSum(float v, float* sh) {
    int t = threadIdx.x;
    v = waveReduceSum(v);
    __syncthreads();
    if ((t & 63) == 0) sh[t >> 6] = v;
    __syncthreads();
    return sh[0] + sh[1] + sh[2] + sh[3];
}
__device__ inline float blockReduceMax(float v, float* sh) {
    int t = threadIdx.x;
    v = waveReduceMax(v);
    __syncthreads();
    if ((t & 63) == 0) sh[t >> 6] = v;
    __syncthreads();
    return fmaxf(fmaxf(sh[0], sh[1]), fmaxf(sh[2], sh[3]));
}

__device__ inline void gload16(const void* g, void* l) {
    __builtin_amdgcn_global_load_lds((const __attribute__((address_space(1))) void*)g,
                                     (__attribute__((address_space(3))) void*)l, 16, 0, 0);
}

// ---------------- prep kernels ----------------

__global__ __launch_bounds__(256) void cast_x(const float* __restrict__ x, u16* __restrict__ xb, int n8) {
    int i = blockIdx.x * blockDim.x + threadIdx.x;
    if (i >= n8) return;
    const float* p = x + (size_t)i * 8;
    union { u16 u[8]; uint4 v; } o;
    #pragma unroll
    for (int j = 0; j < 8; ++j) o.u[j] = f2bf(p[j]);
    ((uint4*)xb)[i] = o.v;
}

__global__ __launch_bounds__(64) void wnorm_all(const float* __restrict__ W1, const float* __restrict__ b1,
                                                const float* __restrict__ W2, const float* __restrict__ b2,
                                                const float* __restrict__ W3, const float* __restrict__ b3,
                                                const float* __restrict__ W4, const float* __restrict__ b4,
                                                const float* __restrict__ W5, const float* __restrict__ b5,
                                                u16* __restrict__ wb, float* __restrict__ biascat) {
    int r = blockIdx.x;
    const float* W; const float* b; int lr;
    if      (r < 20)   { W = W1; b = b1; lr = r; }
    else if (r < 120)  { W = W2; b = b2; lr = r - 20; }
    else if (r < 620)  { W = W3; b = b3; lr = r - 120; }
    else if (r < 2620) { W = W4; b = b4; lr = r - 620; }
    else               { W = W5; b = b5; lr = r - 2620; }
    int t = threadIdx.x;
    const float* p = W + (size_t)lr * FEAT + t * 8;
    float v[8]; float ss = 0.f;
    #pragma unroll
    for (int j = 0; j < 8; ++j) { v[j] = p[j]; ss += v[j] * v[j]; }
    ss = waveReduceSum(ss);
    float inv = 1.0f / fmaxf(sqrtf(ss), 1e-12f);
    union { u16 u[8]; uint4 q; } o;
    #pragma unroll
    for (int j = 0; j < 8; ++j) o.u[j] = f2bf(v[j] * inv);
    ((uint4*)(wb + (size_t)r * FEAT))[t] = o.q;
    if (t == 0) biascat[r] = b[lr];
}

// ---------------- GEMM ----------------
// 128x128x64 tile, 4 waves 2x2, global_load_lds w16, XOR-swizzled LDS,
// 2-phase double-buffered prefetch (issue STAGE(t+1) before compute(t)).
// Output is bf16. STATS: per-(row, coltile) softmax partials (max, sumexp).

#define BM 128
#define BN 128
#define BK 64
#define KITERS (FEAT / BK)

template <bool STATS>
__global__ __launch_bounds__(256) void gemm_bt(const u16* __restrict__ A, const u16* __restrict__ Bw,
                                               const float* __restrict__ bias, u16* __restrict__ C,
                                               int N, int ldc,
                                               float* __restrict__ pmax, float* __restrict__ psum, int nct) {
    __shared__ u16 sAB[2][2 * BM * BK];        // 2 x 32 KB double buffer
    const int t = threadIdx.x;
    const int lane = t & 63, w = t >> 6;
    const int lane15 = lane & 15, q = lane >> 4;
    const int wr = w >> 1, wc = w & 1;
    const int r0 = blockIdx.x * BM, c0 = blockIdx.y * BN;

    f32x4 acc[4][4];
    #pragma unroll
    for (int m = 0; m < 4; ++m)
        #pragma unroll
        for (int n = 0; n < 4; ++n) acc[m][n] = f32x4{0.f, 0.f, 0.f, 0.f};

    // per-thread staging geometry (fixed across iters)
    const int chunkBase = w * 64 + lane;       // within the 256-thread pass i
    auto stage = [&](int kt, int buf) {
        char* sAb = (char*)sAB[buf];
        char* sBb = (char*)(sAB[buf] + BM * BK);
        #pragma unroll
        for (int i = 0; i < 4; ++i) {
            int chunk = i * 256 + chunkBase;    // 0..1023
            int row = chunk >> 3, blk = chunk & 7;
            int srck = 8 * (blk ^ (row & 7));   // swizzled source k (bf16 idx)
            gload16(A + (size_t)(r0 + row) * FEAT + kt + srck, sAb + (size_t)(i * 4 + w) * 1024);
            int brow = c0 + row; if (brow >= N) brow = N - 1;
            gload16(Bw + (size_t)brow * FEAT + kt + srck, sBb + (size_t)(i * 4 + w) * 1024);
        }
    };

    stage(0, 0);
    __syncthreads();
    for (int ki = 0; ki < KITERS; ++ki) {
        int cur = ki & 1;
        if (ki + 1 < KITERS) stage((ki + 1) * BK, cur ^ 1);
        char* sAb = (char*)sAB[cur];
        char* sBb = (char*)(sAB[cur] + BM * BK);
        #pragma unroll
        for (int ks = 0; ks < 2; ++ks) {
            const int kko = ks * 4 + q;
            bf16x8 af[4], bv[4];
            #pragma unroll
            for (int m = 0; m < 4; ++m) {
                int row = wr * 64 + m * 16 + lane15;
                af[m] = *reinterpret_cast<const bf16x8*>(sAb + row * 128 + 16 * (kko ^ (row & 7)));
            }
            #pragma unroll
            for (int n = 0; n < 4; ++n) {
                int row = wc * 64 + n * 16 + lane15;
                bv[n] = *reinterpret_cast<const bf16x8*>(sBb + row * 128 + 16 * (kko ^ (row & 7)));
            }
            #pragma unroll
            for (int m = 0; m < 4; ++m)
                #pragma unroll
                for (int n = 0; n < 4; ++n)
                    acc[m][n] = __builtin_amdgcn_mfma_f32_16x16x32_bf16(af[m], bv[n], acc[m][n], 0, 0, 0);
        }
        __syncthreads();
    }

    // bias add
    bool cval[4];
    #pragma unroll
    for (int n = 0; n < 4; ++n) {
        int col = c0 + wc * 64 + n * 16 + lane15;
        cval[n] = (col < N);
        float bvv = bias[cval[n] ? col : (N - 1)];
        #pragma unroll
        for (int m = 0; m < 4; ++m)
            #pragma unroll
            for (int j = 0; j < 4; ++j) acc[m][n][j] += bvv;
    }

    if (STATS) {
        float* fsh = (float*)sAB;   // LDS reuse after final barrier
        float rm[4][4];
        #pragma unroll
        for (int m = 0; m < 4; ++m)
            #pragma unroll
            for (int j = 0; j < 4; ++j) {
                float v = -1e30f;
                #pragma unroll
                for (int n = 0; n < 4; ++n) if (cval[n]) v = fmaxf(v, acc[m][n][j]);
                #pragma unroll
                for (int d = 1; d < 16; d <<= 1) v = fmaxf(v, __shfl_xor(v, d));
                rm[m][j] = v;
            }
        if (lane15 == 0) {
            #pragma unroll
            for (int m = 0; m < 4; ++m)
                #pragma unroll
                for (int j = 0; j < 4; ++j)
                    fsh[wc * 128 + wr * 64 + m * 16 + q * 4 + j] = rm[m][j];
        }
        __syncthreads();
        float bm[4][4];
        #pragma unroll
        for (int m = 0; m < 4; ++m)
            #pragma unroll
            for (int j = 0; j < 4; ++j) {
                int lr = wr * 64 + m * 16 + q * 4 + j;
                bm[m][j] = fmaxf(fsh[lr], fsh[128 + lr]);
            }
        float sm[4][4];
        #pragma unroll
        for (int m = 0; m < 4; ++m)
            #pragma unroll
            for (int j = 0; j < 4; ++j) {
                float s = 0.f;
                #pragma unroll
                for (int n = 0; n < 4; ++n) if (cval[n]) s += __expf(acc[m][n][j] - bm[m][j]);
                #pragma unroll
                for (int d = 1; d < 16; d <<= 1) s += __shfl_xor(s, d);
                sm[m][j] = s;
            }
        if (lane15 == 0) {
            #pragma unroll
            for (int m = 0; m < 4; ++m)
                #pragma unroll
                for (int j = 0; j < 4; ++j)
                    fsh[256 + wc * 128 + wr * 64 + m * 16 + q * 4 + j] = sm[m][j];
        }
        __syncthreads();
        if (wc == 0 && lane15 == 0) {
            #pragma unroll
            for (int m = 0; m < 4; ++m)
                #pragma unroll
                for (int j = 0; j < 4; ++j) {
                    int lr = wr * 64 + m * 16 + q * 4 + j;
                    size_t idx = (size_t)(r0 + lr) * nct + blockIdx.y;
                    pmax[idx] = bm[m][j];
                    psum[idx] = fsh[256 + lr] + fsh[256 + 128 + lr];
                }
        }
    }

    // store bf16
    #pragma unroll
    for (int m = 0; m < 4; ++m) {
        #pragma unroll
        for (int n = 0; n < 4; ++n) {
            int col = c0 + wc * 64 + n * 16 + lane15;
            if (col < N) {
                int rbase = r0 + wr * 64 + m * 16 + q * 4;
                #pragma unroll
                for (int j = 0; j < 4; ++j)
                    C[(size_t)(rbase + j) * ldc + col] = f2bf(acc[m][n][j]);
            }
        }
    }
}

// ---------------- row-stat merge + CE (wave per row) ----------------

__global__ __launch_bounds__(256) void rowreduce_ce(const float* __restrict__ pmax, const float* __restrict__ psum,
                                                    int nct, const u16* __restrict__ l5b, const int* __restrict__ tgt,
                                                    float* __restrict__ logsB, float* __restrict__ cerow) {
    int w = threadIdx.x >> 6, lane = threadIdx.x & 63;
    int b = blockIdx.x * 4 + w;
    if (b >= BATCH) return;
    const float* pm = pmax + (size_t)b * nct;
    const float* ps = psum + (size_t)b * nct;
    float gm = -1e30f;
    for (int i = lane; i < nct; i += 64) gm = fmaxf(gm, pm[i]);
    gm = waveReduceMax(gm);
    float s = 0.f;
    for (int i = lane; i < nct; i += 64) s += ps[i] * __expf(pm[i] - gm);
    s = waveReduceSum(s);
    float ls = gm + __logf(s);
    if (lane == 0) {
        logsB[b] = ls;
        int tg = tgt[b];
        cerow[b] = -(bfu(l5b[(size_t)b * NC5 + tg]) - ls);
    }
}

// ---------------- fused probabilities + all JSDs (block per row) ----------------

__global__ __launch_bounds__(256) void probs_all(const u16* __restrict__ l5b, float* __restrict__ out,
                                                 const u16* __restrict__ pcat, const float* __restrict__ logsB,
                                                 float* __restrict__ j12, float* __restrict__ j23,
                                                 float* __restrict__ j34, float* __restrict__ j45) {
    __shared__ u16 P5[NC5];
    __shared__ float PC[LDP];
    __shared__ float sh[4];
    int b = blockIdx.x, t = threadIdx.x;
    float ls = logsB[b];
    float* orow = out + (size_t)b * NC5;
    const u16* lrow = l5b + (size_t)b * NC5;
    const u16* prow = pcat + (size_t)b * LDP;

    for (int c = t; c < LDP / 8; c += 256) {
        uint4 raw = ((const uint4*)prow)[c];
        const u16* rp = (const u16*)&raw;
        #pragma unroll
        for (int k = 0; k < 8; ++k) PC[c * 8 + k] = bfu(rp[k]);
    }
    for (int c = t; c < NC5 / 8; c += 256) {
        uint4 raw = ((const uint4*)lrow)[c];
        const u16* rp = (const u16*)&raw;
        f32x4 p0, p1;
        #pragma unroll
        for (int k = 0; k < 4; ++k) p0[k] = __expf(bfu(rp[k]) - ls);
        #pragma unroll
        for (int k = 0; k < 4; ++k) p1[k] = __expf(bfu(rp[4 + k]) - ls);
        ((f32x4*)orow)[c * 2] = p0;
        ((f32x4*)orow)[c * 2 + 1] = p1;
        union { u16 u[8]; uint4 v; } pk;
        #pragma unroll
        for (int k = 0; k < 4; ++k) pk.u[k] = f2bf(p0[k]);
        #pragma unroll
        for (int k = 0; k < 4; ++k) pk.u[4 + k] = f2bf(p1[k]);
        ((uint4*)P5)[c] = pk.v;
    }
    __syncthreads();

    auto softmax_seg = [&](int off, int C) {
        float m = -1e30f;
        for (int c = t; c < C; c += 256) m = fmaxf(m, PC[off + c]);
        m = blockReduceMax(m, sh);
        float s = 0.f;
        for (int c = t; c < C; c += 256) { float e = __expf(PC[off + c] - m); PC[off + c] = e; s += e; }
        s = blockReduceSum(s, sh);
        float inv = 1.0f / s;
        for (int c = t; c < C; c += 256) PC[off + c] *= inv;
    };
    softmax_seg(0, NC1);
    softmax_seg(20, NC2);
    softmax_seg(120, NC3);
    softmax_seg(620, NC4);
    __syncthreads();

    {   // jsd45: agg p5 (fan 5) vs p4
        float klpm = 0.f, klqm = 0.f;
        for (int g = t; g < NC4; g += 256) {
            float qv = 0.f;
            #pragma unroll
            for (int f = 0; f < 5; ++f) qv += bfu(P5[5 * g + f]);
            float pp = PC[620 + g];
            float mm = 0.5f * (qv + pp);
            float lm = __logf(mm + 1e-8f);
            klpm += qv * (__logf(qv + 1e-8f) - lm);
            klqm += pp * (__logf(pp + 1e-8f) - lm);
        }
        float tot = blockReduceSum(0.5f * (klpm + klqm), sh);
        if (t == 0) j45[b] = tot;
    }
    auto jsd_seg = [&](int childOff, int fan, int parentOff, int nPar, float* dst) {
        float klpm = 0.f, klqm = 0.f;
        for (int g = t; g < nPar; g += 256) {
            float qv = 0.f;
            for (int f = 0; f < fan; ++f) qv += PC[childOff + g * fan + f];
            float pp = PC[parentOff + g];
            float mm = 0.5f * (qv + pp);
            float lm = __logf(mm + 1e-8f);
            klpm += qv * (__logf(qv + 1e-8f) - lm);
            klqm += pp * (__logf(pp + 1e-8f) - lm);
        }
        float tot = blockReduceSum(0.5f * (klpm + klqm), sh);
        if (t == 0) dst[b] = tot;
    };
    jsd_seg(620, 4, 120, NC3, j34);
    jsd_seg(120, 5, 20, NC2, j23);
    jsd_seg(20, 5, 0, NC1, j12);
}

// ---------------- weight cosine terms ----------------

__global__ __launch_bounds__(64) void wcos(const float* __restrict__ Wp, const float* __restrict__ Wc,
                                           int fan, float* __restrict__ outBuf) {
    int j = blockIdx.x; int t = threadIdx.x;
    float hat[8] = {0, 0, 0, 0, 0, 0, 0, 0};
    for (int c = 0; c < fan; ++c) {
        const float* cr = Wc + ((size_t)(j * fan + c)) * FEAT + t * 8;
        float v[8]; float ss = 0.f;
        #pragma unroll
        for (int i = 0; i < 8; ++i) { v[i] = cr[i]; ss += v[i] * v[i]; }
        ss = waveReduceSum(ss);
        float inv = 1.0f / fmaxf(sqrtf(ss), 1e-12f);
        #pragma unroll
        for (int i = 0; i < 8; ++i) hat[i] += v[i] * inv;
    }
    float hs = 0.f;
    #pragma unroll
    for (int i = 0; i < 8; ++i) hs += hat[i] * hat[i];
    hs = waveReduceSum(hs);
    float hinv = 1.0f / fmaxf(sqrtf(hs), 1e-12f);
    const float* pr = Wp + (size_t)j * FEAT + t * 8;
    float ps = 0.f, dot = 0.f;
    #pragma unroll
    for (int i = 0; i < 8; ++i) { float pv = pr[i]; ps += pv * pv; dot += pv * hat[i]; }
    ps = waveReduceSum(ps);
    dot = waveReduceSum(dot);
    if (t == 0) outBuf[j] = dot * hinv / fmaxf(sqrtf(ps), 1e-12f);
}

__global__ __launch_bounds__(256) void finalize(const float* __restrict__ ce, const float* __restrict__ j45,
                                                const float* __restrict__ j34, const float* __restrict__ j23,
                                                const float* __restrict__ j12, const float* __restrict__ c45,
                                                const float* __restrict__ c34, const float* __restrict__ c23,
                                                const float* __restrict__ c12, float* __restrict__ lossOut) {
    __shared__ float sh[4];
    auto meanArr = [&](const float* a, int n) {
        float s = 0.f;
        for (int i = threadIdx.x; i < n; i += 256) s += a[i];
        s = blockReduceSum(s, sh);
        return s / n;
    };
    float loss = meanArr(ce, BATCH);
    loss += meanArr(j45, BATCH) + meanArr(j34, BATCH) + meanArr(j23, BATCH) + meanArr(j12, BATCH);
    loss -= meanArr(c45, NC4) + meanArr(c34, NC3) + meanArr(c23, NC2) + meanArr(c12, NC1);
    if (threadIdx.x == 0) *lossOut = loss;
}

// ---------------- launch ----------------

extern "C" void kernel_launch(void* const* d_in, const int* in_sizes, int n_in,
                              void* d_out, int out_size, void* d_ws, size_t ws_size,
                              hipStream_t stream) {
    const float* x  = (const float*)d_in[0];
    const int*   tg = (const int*)d_in[1];
    const float* W1 = (const float*)d_in[2];  const float* b1 = (const float*)d_in[3];
    const float* W2 = (const float*)d_in[4];  const float* b2 = (const float*)d_in[5];
    const float* W3 = (const float*)d_in[6];  const float* b3 = (const float*)d_in[7];
    const float* W4 = (const float*)d_in[8];  const float* b4 = (const float*)d_in[9];
    const float* W5 = (const float*)d_in[10]; const float* b5 = (const float*)d_in[11];
    float* out = (float*)d_out;

    const int NCT = (NC5 + BN - 1) / BN;   // 79 column tiles for l5

    char* ws = (char*)d_ws;
    size_t off = 0;
    auto alloc = [&](size_t bytes) { void* p = ws + off; off = (off + bytes + 255) & ~(size_t)255; return p; };
    u16*   xb      = (u16*)alloc((size_t)BATCH * FEAT * 2);
    u16*   wb      = (u16*)alloc((size_t)NTOT * FEAT * 2);
    float* biascat = (float*)alloc((size_t)NTOT * 4);
    u16*   pcat    = (u16*)alloc((size_t)BATCH * LDP * 2);
    u16*   l5b     = (u16*)alloc((size_t)BATCH * NC5 * 2);
    float* pmax    = (float*)alloc((size_t)BATCH * NCT * 4);
    float* psum    = (float*)alloc((size_t)BATCH * NCT * 4);
    float* logsB   = (float*)alloc((size_t)BATCH * 4);
    float* cerow   = (float*)alloc((size_t)BATCH * 4);
    float* j45     = (float*)alloc((size_t)BATCH * 4);
    float* j34     = (float*)alloc((size_t)BATCH * 4);
    float* j23     = (float*)alloc((size_t)BATCH * 4);
    float* j12     = (float*)alloc((size_t)BATCH * 4);
    float* c45     = (float*)alloc((size_t)NC4 * 4);
    float* c34     = (float*)alloc((size_t)NC3 * 4);
    float* c23     = (float*)alloc((size_t)NC2 * 4);
    float* c12     = (float*)alloc((size_t)NC1 * 4);

    cast_x<<<(BATCH * FEAT / 8 + 255) / 256, 256, 0, stream>>>(x, xb, BATCH * FEAT / 8);
    wnorm_all<<<NTOT, 64, 0, stream>>>(W1, b1, W2, b2, W3, b3, W4, b4, W5, b5, wb, biascat);

    gemm_bt<false><<<dim3(BATCH / BM, (NCAT + BN - 1) / BN), 256, 0, stream>>>(
        xb, wb, biascat, pcat, NCAT, LDP, nullptr, nullptr, 0);
    gemm_bt<true><<<dim3(BATCH / BM, NCT), 256, 0, stream>>>(
        xb, wb + (size_t)NCAT * FEAT, biascat + NCAT, l5b, NC5, NC5, pmax, psum, NCT);

    rowreduce_ce<<<BATCH / 4, 256, 0, stream>>>(pmax, psum, NCT, l5b, tg, logsB, cerow);
    probs_all<<<BATCH, 256, 0, stream>>>(l5b, out, pcat, logsB, j12, j23, j34, j45);

    wcos<<<NC4, 64, 0, stream>>>(W4, W5, 5, c45);
    wcos<<<NC3, 64, 0, stream>>>(W3, W4, 4, c34);
    wcos<<<NC2, 64, 0, stream>>>(W2, W3, 5, c23);
    wcos<<<NC1, 64, 0, stream>>>(W1, W2, 5, c12);

    finalize<<<1, 256, 0, stream>>>(cerow, j45, j34, j23, j12, c45, c34, c23, c12,
                                    out + (size_t)BATCH * NC5);
}

// Round 4
// 425.936 us; speedup vs baseline: 1.7951x; 1.1590x over previous
//
#include <hip/hip_runtime.h>
#include <hip/hip_bf16.h>
#include <stdint.h>

typedef unsigned short u16;
typedef __bf16 bf16x8 __attribute__((ext_vector_type(8)));
typedef float f32x4 __attribute__((ext_vector_type(4)));

#define FEAT 512
#define BATCH 8192
#define NC1 20
#define NC2 100
#define NC3 500
#define NC4 2000
#define NC5 10000
#define NCAT 2620
#define LDP 2624          // padded leading dim for pcat (uint4-clean bf16 rows)
#define NTOT 12620

__device__ inline u16 f2bf(float f) {
    unsigned int u = __builtin_bit_cast(unsigned int, f);
    unsigned int r = (u + 0x7FFFu + ((u >> 16) & 1u)) >> 16;
    return (u16)r;
}
__device__ inline float bfu(u16 u) {
    return __builtin_bit_cast(float, (unsigned int)u << 16);
}

__device__ inline float waveReduceSum(float v) {
    #pragma unroll
    for (int off = 32; off > 0; off >>= 1) v += __shfl_xor(v, off);
    return v;
}
__device__ inline float waveReduceMax(float v) {
    #pragma unroll
    for (int off = 32; off > 0; off >>= 1) v = fmaxf(v, __shfl_xor(v, off));
    return v;
}
__device__ inline float blockReduceSum(float v, float* sh) {
    int t = threadIdx.x;
    v = waveReduceSum(v);
    __syncthreads();
    if ((t & 63) == 0) sh[t >> 6] = v;
    __syncthreads();
    return sh[0] + sh[1] + sh[2] + sh[3];
}
__device__ inline float blockReduceMax(float v, float* sh) {
    int t = threadIdx.x;
    v = waveReduceMax(v);
    __syncthreads();
    if ((t & 63) == 0) sh[t >> 6] = v;
    __syncthreads();
    return fmaxf(fmaxf(sh[0], sh[1]), fmaxf(sh[2], sh[3]));
}

__device__ inline void gload16(const void* g, void* l) {
    __builtin_amdgcn_global_load_lds((const __attribute__((address_space(1))) void*)g,
                                     (__attribute__((address_space(3))) void*)l, 16, 0, 0);
}

// ---------------- prep kernels ----------------

__global__ __launch_bounds__(256) void cast_x(const float* __restrict__ x, u16* __restrict__ xb, int n8) {
    int i = blockIdx.x * blockDim.x + threadIdx.x;
    if (i >= n8) return;
    const float* p = x + (size_t)i * 8;
    union { u16 u[8]; uint4 v; } o;
    #pragma unroll
    for (int j = 0; j < 8; ++j) o.u[j] = f2bf(p[j]);
    ((uint4*)xb)[i] = o.v;
}

__global__ __launch_bounds__(64) void wnorm_all(const float* __restrict__ W1, const float* __restrict__ b1,
                                                const float* __restrict__ W2, const float* __restrict__ b2,
                                                const float* __restrict__ W3, const float* __restrict__ b3,
                                                const float* __restrict__ W4, const float* __restrict__ b4,
                                                const float* __restrict__ W5, const float* __restrict__ b5,
                                                u16* __restrict__ wb, float* __restrict__ biascat) {
    int r = blockIdx.x;
    const float* W; const float* b; int lr;
    if      (r < 20)   { W = W1; b = b1; lr = r; }
    else if (r < 120)  { W = W2; b = b2; lr = r - 20; }
    else if (r < 620)  { W = W3; b = b3; lr = r - 120; }
    else if (r < 2620) { W = W4; b = b4; lr = r - 620; }
    else               { W = W5; b = b5; lr = r - 2620; }
    int t = threadIdx.x;
    const float* p = W + (size_t)lr * FEAT + t * 8;
    float v[8]; float ss = 0.f;
    #pragma unroll
    for (int j = 0; j < 8; ++j) { v[j] = p[j]; ss += v[j] * v[j]; }
    ss = waveReduceSum(ss);
    float inv = 1.0f / fmaxf(sqrtf(ss), 1e-12f);
    union { u16 u[8]; uint4 q; } o;
    #pragma unroll
    for (int j = 0; j < 8; ++j) o.u[j] = f2bf(v[j] * inv);
    ((uint4*)(wb + (size_t)r * FEAT))[t] = o.q;
    if (t == 0) biascat[r] = b[lr];
}

// ---------------- GEMM ----------------
// 256x256 tile, 8 waves (2 row-groups x 4 col-groups), BK=64, double-buffered
// global_load_lds w16, XOR-swizzled LDS, TRANSPOSED mfma (lane holds 4
// consecutive output cols -> uint2 bf16 stores). STATS: per-(row, coltile)
// softmax partials.

#define BM 256
#define BN 256
#define BK 64
#define KITERS (FEAT / BK)

template <bool STATS>
__global__ __launch_bounds__(512, 2) void gemm_bt(const u16* __restrict__ A, const u16* __restrict__ Bw,
                                                  const float* __restrict__ bias, u16* __restrict__ C,
                                                  int N, int ldc,
                                                  float* __restrict__ pmax, float* __restrict__ psum, int nct) {
    __shared__ u16 sAB[2][2 * BM * BK];        // 2 x 64 KB double buffer
    const int t = threadIdx.x;
    const int lane = t & 63, wid = t >> 6;
    const int lane15 = lane & 15, q = lane >> 4;
    const int wr = wid >> 2, wcol = wid & 3;

    // XCD-aware bijective swizzle (grid size divisible by 8 for both GEMMs)
    int nwg = gridDim.x * gridDim.y;
    int lid = blockIdx.y * gridDim.x + blockIdx.x;
    int cpx = nwg >> 3;
    int swz = (lid & 7) * cpx + (lid >> 3);
    int bx = swz % gridDim.x, by = swz / gridDim.x;
    const int r0 = bx * BM, c0 = by * BN;

    f32x4 acc[8][4];
    #pragma unroll
    for (int m = 0; m < 8; ++m)
        #pragma unroll
        for (int n = 0; n < 4; ++n) acc[m][n] = f32x4{0.f, 0.f, 0.f, 0.f};

    auto stage = [&](int kt, int buf) {
        char* base = (char*)sAB[buf];
        #pragma unroll
        for (int p = 0; p < 8; ++p) {
            int chunk = p * 512 + t;            // 0..4095 (16B each)
            int row = chunk >> 3, blk = chunk & 7;
            int srck = 8 * (blk ^ (row & 7));   // swizzled source k (bf16 idx)
            const u16* g;
            if (p < 4) {
                g = A + (size_t)(r0 + row) * FEAT + kt + srck;
            } else {
                int brow = c0 + (row - 256); if (brow >= N) brow = N - 1;
                g = Bw + (size_t)brow * FEAT + kt + srck;
            }
            gload16(g, base + (size_t)chunk * 16);
        }
    };

    stage(0, 0);
    __syncthreads();
    for (int ki = 0; ki < KITERS; ++ki) {
        int cur = ki & 1;
        if (ki + 1 < KITERS) stage((ki + 1) * BK, cur ^ 1);
        char* sAb = (char*)sAB[cur];
        char* sBb = sAb + BM * BK * 2;
        #pragma unroll
        for (int ks = 0; ks < 2; ++ks) {
            const int kko = ks * 4 + q;
            bf16x8 af[8], bv[4];
            #pragma unroll
            for (int m = 0; m < 8; ++m) {
                int row = wr * 128 + m * 16 + lane15;
                af[m] = *reinterpret_cast<const bf16x8*>(sAb + row * 128 + 16 * (kko ^ (row & 7)));
            }
            #pragma unroll
            for (int n = 0; n < 4; ++n) {
                int row = wcol * 64 + n * 16 + lane15;
                bv[n] = *reinterpret_cast<const bf16x8*>(sBb + row * 128 + 16 * (kko ^ (row & 7)));
            }
            #pragma unroll
            for (int m = 0; m < 8; ++m)
                #pragma unroll
                for (int n = 0; n < 4; ++n)
                    acc[m][n] = __builtin_amdgcn_mfma_f32_16x16x32_bf16(bv[n], af[m], acc[m][n], 0, 0, 0);
        }
        __syncthreads();
    }

    // transposed D layout: lane holds row = r0+wr*128+m*16+lane15,
    // cols cb..cb+3 with cb = c0+wcol*64+n*16+q*4  (N % 4 == 0)
    bool vld[4]; int cb[4];
    #pragma unroll
    for (int n = 0; n < 4; ++n) {
        cb[n] = c0 + wcol * 64 + n * 16 + q * 4;
        vld[n] = (cb[n] < N);
        if (vld[n]) {
            float b0 = bias[cb[n]], b1 = bias[cb[n] + 1], b2 = bias[cb[n] + 2], b3 = bias[cb[n] + 3];
            #pragma unroll
            for (int m = 0; m < 8; ++m) {
                acc[m][n][0] += b0; acc[m][n][1] += b1;
                acc[m][n][2] += b2; acc[m][n][3] += b3;
            }
        }
    }

    if (STATS) {
        float* fmx = (float*)sAB;            // [256][4] row-max per wcol
        float* fsm = fmx + 1024;             // [256][4] row-sumexp per wcol
        float bm[8];
        #pragma unroll
        for (int m = 0; m < 8; ++m) {
            float v = -1e30f;
            #pragma unroll
            for (int n = 0; n < 4; ++n)
                if (vld[n]) {
                    #pragma unroll
                    for (int j = 0; j < 4; ++j) v = fmaxf(v, acc[m][n][j]);
                }
            v = fmaxf(v, __shfl_xor(v, 16));
            v = fmaxf(v, __shfl_xor(v, 32));
            bm[m] = v;
        }
        if (lane < 16) {
            #pragma unroll
            for (int m = 0; m < 8; ++m)
                fmx[(wr * 128 + m * 16 + lane15) * 4 + wcol] = bm[m];
        }
        __syncthreads();
        #pragma unroll
        for (int m = 0; m < 8; ++m) {
            int row = wr * 128 + m * 16 + lane15;
            bm[m] = fmaxf(fmaxf(fmx[row * 4], fmx[row * 4 + 1]),
                          fmaxf(fmx[row * 4 + 2], fmx[row * 4 + 3]));
        }
        float sm[8];
        #pragma unroll
        for (int m = 0; m < 8; ++m) {
            float s = 0.f;
            #pragma unroll
            for (int n = 0; n < 4; ++n)
                if (vld[n]) {
                    #pragma unroll
                    for (int j = 0; j < 4; ++j) s += __expf(acc[m][n][j] - bm[m]);
                }
            s += __shfl_xor(s, 16);
            s += __shfl_xor(s, 32);
            sm[m] = s;
        }
        if (lane < 16) {
            #pragma unroll
            for (int m = 0; m < 8; ++m)
                fsm[(wr * 128 + m * 16 + lane15) * 4 + wcol] = sm[m];
        }
        __syncthreads();
        if (t < 256) {
            float m4 = fmaxf(fmaxf(fmx[t * 4], fmx[t * 4 + 1]), fmaxf(fmx[t * 4 + 2], fmx[t * 4 + 3]));
            float s4 = fsm[t * 4] + fsm[t * 4 + 1] + fsm[t * 4 + 2] + fsm[t * 4 + 3];
            size_t idx = (size_t)(r0 + t) * nct + by;
            pmax[idx] = m4;
            psum[idx] = s4;
        }
    }

    // store bf16 as uint2 (4 consecutive cols per lane)
    #pragma unroll
    for (int m = 0; m < 8; ++m) {
        int row = r0 + wr * 128 + m * 16 + lane15;
        #pragma unroll
        for (int n = 0; n < 4; ++n) {
            if (vld[n]) {
                union { u16 u[4]; uint2 v; } pk;
                #pragma unroll
                for (int j = 0; j < 4; ++j) pk.u[j] = f2bf(acc[m][n][j]);
                *reinterpret_cast<uint2*>(&C[(size_t)row * ldc + cb[n]]) = pk.v;
            }
        }
    }
}

// ---------------- row-stat merge + CE (wave per row) ----------------

__global__ __launch_bounds__(256) void rowreduce_ce(const float* __restrict__ pmax, const float* __restrict__ psum,
                                                    int nct, const u16* __restrict__ l5b, const int* __restrict__ tgt,
                                                    float* __restrict__ logsB, float* __restrict__ cerow) {
    int w = threadIdx.x >> 6, lane = threadIdx.x & 63;
    int b = blockIdx.x * 4 + w;
    if (b >= BATCH) return;
    const float* pm = pmax + (size_t)b * nct;
    const float* ps = psum + (size_t)b * nct;
    float gm = -1e30f;
    for (int i = lane; i < nct; i += 64) gm = fmaxf(gm, pm[i]);
    gm = waveReduceMax(gm);
    float s = 0.f;
    for (int i = lane; i < nct; i += 64) s += ps[i] * __expf(pm[i] - gm);
    s = waveReduceSum(s);
    float ls = gm + __logf(s);
    if (lane == 0) {
        logsB[b] = ls;
        int tg = tgt[b];
        cerow[b] = -(bfu(l5b[(size_t)b * NC5 + tg]) - ls);
    }
}

// ---------------- fused probabilities + all JSDs (block per row) ----------------

__global__ __launch_bounds__(256) void probs_all(const u16* __restrict__ l5b, float* __restrict__ out,
                                                 const u16* __restrict__ pcat, const float* __restrict__ logsB,
                                                 float* __restrict__ j12, float* __restrict__ j23,
                                                 float* __restrict__ j34, float* __restrict__ j45) {
    __shared__ u16 P5[NC5];
    __shared__ float PC[LDP];
    __shared__ float sh[4];
    int b = blockIdx.x, t = threadIdx.x;
    float ls = logsB[b];
    float* orow = out + (size_t)b * NC5;
    const u16* lrow = l5b + (size_t)b * NC5;
    const u16* prow = pcat + (size_t)b * LDP;

    for (int c = t; c < LDP / 8; c += 256) {
        uint4 raw = ((const uint4*)prow)[c];
        const u16* rp = (const u16*)&raw;
        #pragma unroll
        for (int k = 0; k < 8; ++k) PC[c * 8 + k] = bfu(rp[k]);
    }
    for (int c = t; c < NC5 / 8; c += 256) {
        uint4 raw = ((const uint4*)lrow)[c];
        const u16* rp = (const u16*)&raw;
        f32x4 p0, p1;
        #pragma unroll
        for (int k = 0; k < 4; ++k) p0[k] = __expf(bfu(rp[k]) - ls);
        #pragma unroll
        for (int k = 0; k < 4; ++k) p1[k] = __expf(bfu(rp[4 + k]) - ls);
        ((f32x4*)orow)[c * 2] = p0;
        ((f32x4*)orow)[c * 2 + 1] = p1;
        union { u16 u[8]; uint4 v; } pk;
        #pragma unroll
        for (int k = 0; k < 4; ++k) pk.u[k] = f2bf(p0[k]);
        #pragma unroll
        for (int k = 0; k < 4; ++k) pk.u[4 + k] = f2bf(p1[k]);
        ((uint4*)P5)[c] = pk.v;
    }
    __syncthreads();

    auto softmax_seg = [&](int off, int C) {
        float m = -1e30f;
        for (int c = t; c < C; c += 256) m = fmaxf(m, PC[off + c]);
        m = blockReduceMax(m, sh);
        float s = 0.f;
        for (int c = t; c < C; c += 256) { float e = __expf(PC[off + c] - m); PC[off + c] = e; s += e; }
        s = blockReduceSum(s, sh);
        float inv = 1.0f / s;
        for (int c = t; c < C; c += 256) PC[off + c] *= inv;
    };
    softmax_seg(0, NC1);
    softmax_seg(20, NC2);
    softmax_seg(120, NC3);
    softmax_seg(620, NC4);
    __syncthreads();

    {   // jsd45: agg p5 (fan 5) vs p4
        float klpm = 0.f, klqm = 0.f;
        for (int g = t; g < NC4; g += 256) {
            float qv = 0.f;
            #pragma unroll
            for (int f = 0; f < 5; ++f) qv += bfu(P5[5 * g + f]);
            float pp = PC[620 + g];
            float mm = 0.5f * (qv + pp);
            float lm = __logf(mm + 1e-8f);
            klpm += qv * (__logf(qv + 1e-8f) - lm);
            klqm += pp * (__logf(pp + 1e-8f) - lm);
        }
        float tot = blockReduceSum(0.5f * (klpm + klqm), sh);
        if (t == 0) j45[b] = tot;
    }
    auto jsd_seg = [&](int childOff, int fan, int parentOff, int nPar, float* dst) {
        float klpm = 0.f, klqm = 0.f;
        for (int g = t; g < nPar; g += 256) {
            float qv = 0.f;
            for (int f = 0; f < fan; ++f) qv += PC[childOff + g * fan + f];
            float pp = PC[parentOff + g];
            float mm = 0.5f * (qv + pp);
            float lm = __logf(mm + 1e-8f);
            klpm += qv * (__logf(qv + 1e-8f) - lm);
            klqm += pp * (__logf(pp + 1e-8f) - lm);
        }
        float tot = blockReduceSum(0.5f * (klpm + klqm), sh);
        if (t == 0) dst[b] = tot;
    };
    jsd_seg(620, 4, 120, NC3, j34);
    jsd_seg(120, 5, 20, NC2, j23);
    jsd_seg(20, 5, 0, NC1, j12);
}

// ---------------- weight cosine terms ----------------

__global__ __launch_bounds__(64) void wcos(const float* __restrict__ Wp, const float* __restrict__ Wc,
                                           int fan, float* __restrict__ outBuf) {
    int j = blockIdx.x; int t = threadIdx.x;
    float hat[8] = {0, 0, 0, 0, 0, 0, 0, 0};
    for (int c = 0; c < fan; ++c) {
        const float* cr = Wc + ((size_t)(j * fan + c)) * FEAT + t * 8;
        float v[8]; float ss = 0.f;
        #pragma unroll
        for (int i = 0; i < 8; ++i) { v[i] = cr[i]; ss += v[i] * v[i]; }
        ss = waveReduceSum(ss);
        float inv = 1.0f / fmaxf(sqrtf(ss), 1e-12f);
        #pragma unroll
        for (int i = 0; i < 8; ++i) hat[i] += v[i] * inv;
    }
    float hs = 0.f;
    #pragma unroll
    for (int i = 0; i < 8; ++i) hs += hat[i] * hat[i];
    hs = waveReduceSum(hs);
    float hinv = 1.0f / fmaxf(sqrtf(hs), 1e-12f);
    const float* pr = Wp + (size_t)j * FEAT + t * 8;
    float ps = 0.f, dot = 0.f;
    #pragma unroll
    for (int i = 0; i < 8; ++i) { float pv = pr[i]; ps += pv * pv; dot += pv * hat[i]; }
    ps = waveReduceSum(ps);
    dot = waveReduceSum(dot);
    if (t == 0) outBuf[j] = dot * hinv / fmaxf(sqrtf(ps), 1e-12f);
}

__global__ __launch_bounds__(256) void finalize(const float* __restrict__ ce, const float* __restrict__ j45,
                                                const float* __restrict__ j34, const float* __restrict__ j23,
                                                const float* __restrict__ j12, const float* __restrict__ c45,
                                                const float* __restrict__ c34, const float* __restrict__ c23,
                                                const float* __restrict__ c12, float* __restrict__ lossOut) {
    __shared__ float sh[4];
    auto meanArr = [&](const float* a, int n) {
        float s = 0.f;
        for (int i = threadIdx.x; i < n; i += 256) s += a[i];
        s = blockReduceSum(s, sh);
        return s / n;
    };
    float loss = meanArr(ce, BATCH);
    loss += meanArr(j45, BATCH) + meanArr(j34, BATCH) + meanArr(j23, BATCH) + meanArr(j12, BATCH);
    loss -= meanArr(c45, NC4) + meanArr(c34, NC3) + meanArr(c23, NC2) + meanArr(c12, NC1);
    if (threadIdx.x == 0) *lossOut = loss;
}

// ---------------- launch ----------------

extern "C" void kernel_launch(void* const* d_in, const int* in_sizes, int n_in,
                              void* d_out, int out_size, void* d_ws, size_t ws_size,
                              hipStream_t stream) {
    const float* x  = (const float*)d_in[0];
    const int*   tg = (const int*)d_in[1];
    const float* W1 = (const float*)d_in[2];  const float* b1 = (const float*)d_in[3];
    const float* W2 = (const float*)d_in[4];  const float* b2 = (const float*)d_in[5];
    const float* W3 = (const float*)d_in[6];  const float* b3 = (const float*)d_in[7];
    const float* W4 = (const float*)d_in[8];  const float* b4 = (const float*)d_in[9];
    const float* W5 = (const float*)d_in[10]; const float* b5 = (const float*)d_in[11];
    float* out = (float*)d_out;

    const int NCT = (NC5 + BN - 1) / BN;   // 40 column tiles for l5

    char* ws = (char*)d_ws;
    size_t off = 0;
    auto alloc = [&](size_t bytes) { void* p = ws + off; off = (off + bytes + 255) & ~(size_t)255; return p; };
    u16*   xb      = (u16*)alloc((size_t)BATCH * FEAT * 2);
    u16*   wb      = (u16*)alloc((size_t)NTOT * FEAT * 2);
    float* biascat = (float*)alloc((size_t)NTOT * 4);
    u16*   pcat    = (u16*)alloc((size_t)BATCH * LDP * 2);
    u16*   l5b     = (u16*)alloc((size_t)BATCH * NC5 * 2);
    float* pmax    = (float*)alloc((size_t)BATCH * NCT * 4);
    float* psum    = (float*)alloc((size_t)BATCH * NCT * 4);
    float* logsB   = (float*)alloc((size_t)BATCH * 4);
    float* cerow   = (float*)alloc((size_t)BATCH * 4);
    float* j45     = (float*)alloc((size_t)BATCH * 4);
    float* j34     = (float*)alloc((size_t)BATCH * 4);
    float* j23     = (float*)alloc((size_t)BATCH * 4);
    float* j12     = (float*)alloc((size_t)BATCH * 4);
    float* c45     = (float*)alloc((size_t)NC4 * 4);
    float* c34     = (float*)alloc((size_t)NC3 * 4);
    float* c23     = (float*)alloc((size_t)NC2 * 4);
    float* c12     = (float*)alloc((size_t)NC1 * 4);

    cast_x<<<(BATCH * FEAT / 8 + 255) / 256, 256, 0, stream>>>(x, xb, BATCH * FEAT / 8);
    wnorm_all<<<NTOT, 64, 0, stream>>>(W1, b1, W2, b2, W3, b3, W4, b4, W5, b5, wb, biascat);

    gemm_bt<false><<<dim3(BATCH / BM, (NCAT + BN - 1) / BN), 512, 0, stream>>>(
        xb, wb, biascat, pcat, NCAT, LDP, nullptr, nullptr, 0);
    gemm_bt<true><<<dim3(BATCH / BM, NCT), 512, 0, stream>>>(
        xb, wb + (size_t)NCAT * FEAT, biascat + NCAT, l5b, NC5, NC5, pmax, psum, NCT);

    rowreduce_ce<<<BATCH / 4, 256, 0, stream>>>(pmax, psum, NCT, l5b, tg, logsB, cerow);
    probs_all<<<BATCH, 256, 0, stream>>>(l5b, out, pcat, logsB, j12, j23, j34, j45);

    wcos<<<NC4, 64, 0, stream>>>(W4, W5, 5, c45);
    wcos<<<NC3, 64, 0, stream>>>(W3, W4, 4, c34);
    wcos<<<NC2, 64, 0, stream>>>(W2, W3, 5, c23);
    wcos<<<NC1, 64, 0, stream>>>(W1, W2, 5, c12);

    finalize<<<1, 256, 0, stream>>>(cerow, j45, j34, j23, j12, c45, c34, c23, c12,
                                    out + (size_t)BATCH * NC5);
}

// Round 5
// 414.925 us; speedup vs baseline: 1.8427x; 1.0265x over previous
//
#include <hip/hip_runtime.h>
#include <hip/hip_bf16.h>
#include <stdint.h>

typedef unsigned short u16;
typedef __bf16 bf16x8 __attribute__((ext_vector_type(8)));
typedef float f32x4 __attribute__((ext_vector_type(4)));

#define FEAT 512
#define BATCH 8192
#define NC1 20
#define NC2 100
#define NC3 500
#define NC4 2000
#define NC5 10000
#define NCAT 2620
#define LDP 2624          // padded leading dim for pcat (uint4-clean bf16 rows)
#define NTOT 12620

__device__ inline u16 f2bf(float f) {
    unsigned int u = __builtin_bit_cast(unsigned int, f);
    unsigned int r = (u + 0x7FFFu + ((u >> 16) & 1u)) >> 16;
    return (u16)r;
}
__device__ inline float bfu(u16 u) {
    return __builtin_bit_cast(float, (unsigned int)u << 16);
}

__device__ inline float waveReduceSum(float v) {
    #pragma unroll
    for (int off = 32; off > 0; off >>= 1) v += __shfl_xor(v, off);
    return v;
}
__device__ inline float waveReduceMax(float v) {
    #pragma unroll
    for (int off = 32; off > 0; off >>= 1) v = fmaxf(v, __shfl_xor(v, off));
    return v;
}
__device__ inline float blockReduceSum(float v, float* sh) {
    int t = threadIdx.x;
    v = waveReduceSum(v);
    __syncthreads();
    if ((t & 63) == 0) sh[t >> 6] = v;
    __syncthreads();
    return sh[0] + sh[1] + sh[2] + sh[3];
}
__device__ inline float blockReduceMax(float v, float* sh) {
    int t = threadIdx.x;
    v = waveReduceMax(v);
    __syncthreads();
    if ((t & 63) == 0) sh[t >> 6] = v;
    __syncthreads();
    return fmaxf(fmaxf(sh[0], sh[1]), fmaxf(sh[2], sh[3]));
}

__device__ inline void gload16(const void* g, void* l) {
    __builtin_amdgcn_global_load_lds((const __attribute__((address_space(1))) void*)g,
                                     (__attribute__((address_space(3))) void*)l, 16, 0, 0);
}

// ---------------- prep kernels ----------------

__global__ __launch_bounds__(256) void cast_x(const float* __restrict__ x, u16* __restrict__ xb, int n8) {
    int i = blockIdx.x * blockDim.x + threadIdx.x;
    if (i >= n8) return;
    const float* p = x + (size_t)i * 8;
    union { u16 u[8]; uint4 v; } o;
    #pragma unroll
    for (int j = 0; j < 8; ++j) o.u[j] = f2bf(p[j]);
    ((uint4*)xb)[i] = o.v;
}

__global__ __launch_bounds__(64) void wnorm_all(const float* __restrict__ W1, const float* __restrict__ b1,
                                                const float* __restrict__ W2, const float* __restrict__ b2,
                                                const float* __restrict__ W3, const float* __restrict__ b3,
                                                const float* __restrict__ W4, const float* __restrict__ b4,
                                                const float* __restrict__ W5, const float* __restrict__ b5,
                                                u16* __restrict__ wb, float* __restrict__ biascat) {
    int r = blockIdx.x;
    const float* W; const float* b; int lr;
    if      (r < 20)   { W = W1; b = b1; lr = r; }
    else if (r < 120)  { W = W2; b = b2; lr = r - 20; }
    else if (r < 620)  { W = W3; b = b3; lr = r - 120; }
    else if (r < 2620) { W = W4; b = b4; lr = r - 620; }
    else               { W = W5; b = b5; lr = r - 2620; }
    int t = threadIdx.x;
    const float* p = W + (size_t)lr * FEAT + t * 8;
    float v[8]; float ss = 0.f;
    #pragma unroll
    for (int j = 0; j < 8; ++j) { v[j] = p[j]; ss += v[j] * v[j]; }
    ss = waveReduceSum(ss);
    float inv = 1.0f / fmaxf(sqrtf(ss), 1e-12f);
    union { u16 u[8]; uint4 q; } o;
    #pragma unroll
    for (int j = 0; j < 8; ++j) o.u[j] = f2bf(v[j] * inv);
    ((uint4*)(wb + (size_t)r * FEAT))[t] = o.q;
    if (t == 0) biascat[r] = b[lr];
}

// ---------------- GEMM ----------------
// 256x256 tile, 8 waves (2x4), BK=64, double-buffered global_load_lds w16,
// XOR-swizzled LDS, transposed mfma (lane holds 4 consecutive output cols),
// counted-vmcnt raw-barrier pipeline (vmcnt(8): next stage stays in flight).

#define BM 256
#define BN 256
#define BK 64
#define KITERS (FEAT / BK)

template <bool STATS>
__global__ __launch_bounds__(512, 2) void gemm_bt(const u16* __restrict__ A, const u16* __restrict__ Bw,
                                                  const float* __restrict__ bias, u16* __restrict__ C,
                                                  int N, int ldc,
                                                  float* __restrict__ pmax, float* __restrict__ psum, int nct) {
    __shared__ u16 sAB[2][2 * BM * BK];        // 2 x 64 KB double buffer
    const int t = threadIdx.x;
    const int lane = t & 63, wid = t >> 6;
    const int lane15 = lane & 15, q = lane >> 4;
    const int wr = wid >> 2, wcol = wid & 3;

    // XCD-aware bijective swizzle (grid sizes divisible by 8)
    int nwg = gridDim.x * gridDim.y;
    int lid = blockIdx.y * gridDim.x + blockIdx.x;
    int cpx = nwg >> 3;
    int swz = (lid & 7) * cpx + (lid >> 3);
    int bx = swz % gridDim.x, by = swz / gridDim.x;
    const int r0 = bx * BM, c0 = by * BN;

    f32x4 acc[8][4];
    #pragma unroll
    for (int m = 0; m < 8; ++m)
        #pragma unroll
        for (int n = 0; n < 4; ++n) acc[m][n] = f32x4{0.f, 0.f, 0.f, 0.f};

    auto stage = [&](int kt, int buf) {
        char* base = (char*)sAB[buf];
        #pragma unroll
        for (int p = 0; p < 8; ++p) {
            int chunk = p * 512 + t;            // 0..4095 (16B each)
            int row = chunk >> 3, blk = chunk & 7;
            int srck = 8 * (blk ^ (row & 7));   // swizzled source k (bf16 idx)
            const u16* g;
            if (p < 4) {
                g = A + (size_t)(r0 + row) * FEAT + kt + srck;
            } else {
                int brow = c0 + (row - 256); if (brow >= N) brow = N - 1;
                g = Bw + (size_t)brow * FEAT + kt + srck;
            }
            gload16(g, base + (size_t)chunk * 16);
        }
    };

    stage(0, 0);            // 8 loads in flight
    stage(BK, 1);           // 16 in flight
    for (int ki = 0; ki < KITERS; ++ki) {
        if (ki + 1 < KITERS) { asm volatile("s_waitcnt vmcnt(8)" ::: "memory"); }
        else                 { asm volatile("s_waitcnt vmcnt(0)" ::: "memory"); }
        __builtin_amdgcn_sched_barrier(0);
        __builtin_amdgcn_s_barrier();
        __builtin_amdgcn_sched_barrier(0);
        char* sAb = (char*)sAB[ki & 1];
        char* sBb = sAb + BM * BK * 2;
        #pragma unroll
        for (int ks = 0; ks < 2; ++ks) {
            const int kko = ks * 4 + q;
            bf16x8 af[8], bv[4];
            #pragma unroll
            for (int m = 0; m < 8; ++m) {
                int row = wr * 128 + m * 16 + lane15;
                af[m] = *reinterpret_cast<const bf16x8*>(sAb + row * 128 + 16 * (kko ^ (row & 7)));
            }
            #pragma unroll
            for (int n = 0; n < 4; ++n) {
                int row = wcol * 64 + n * 16 + lane15;
                bv[n] = *reinterpret_cast<const bf16x8*>(sBb + row * 128 + 16 * (kko ^ (row & 7)));
            }
            #pragma unroll
            for (int m = 0; m < 8; ++m)
                #pragma unroll
                for (int n = 0; n < 4; ++n)
                    acc[m][n] = __builtin_amdgcn_mfma_f32_16x16x32_bf16(bv[n], af[m], acc[m][n], 0, 0, 0);
        }
        __builtin_amdgcn_sched_barrier(0);
        __builtin_amdgcn_s_barrier();
        __builtin_amdgcn_sched_barrier(0);
        if (ki + 2 < KITERS) stage((ki + 2) * BK, ki & 1);
    }

    // transposed D layout: lane holds row = r0+wr*128+m*16+lane15,
    // cols cb..cb+3 with cb = c0+wcol*64+n*16+q*4  (N % 4 == 0)
    bool vld[4]; int cb[4];
    #pragma unroll
    for (int n = 0; n < 4; ++n) {
        cb[n] = c0 + wcol * 64 + n * 16 + q * 4;
        vld[n] = (cb[n] < N);
        if (vld[n]) {
            float b0 = bias[cb[n]], b1 = bias[cb[n] + 1], b2 = bias[cb[n] + 2], b3 = bias[cb[n] + 3];
            #pragma unroll
            for (int m = 0; m < 8; ++m) {
                acc[m][n][0] += b0; acc[m][n][1] += b1;
                acc[m][n][2] += b2; acc[m][n][3] += b3;
            }
        }
    }

    if (STATS) {
        float* fmx = (float*)sAB;            // [256][4] row-max per wcol
        float* fsm = fmx + 1024;             // [256][4] row-sumexp per wcol
        float bm[8];
        #pragma unroll
        for (int m = 0; m < 8; ++m) {
            float v = -1e30f;
            #pragma unroll
            for (int n = 0; n < 4; ++n)
                if (vld[n]) {
                    #pragma unroll
                    for (int j = 0; j < 4; ++j) v = fmaxf(v, acc[m][n][j]);
                }
            v = fmaxf(v, __shfl_xor(v, 16));
            v = fmaxf(v, __shfl_xor(v, 32));
            bm[m] = v;
        }
        if (lane < 16) {
            #pragma unroll
            for (int m = 0; m < 8; ++m)
                fmx[(wr * 128 + m * 16 + lane15) * 4 + wcol] = bm[m];
        }
        __syncthreads();
        #pragma unroll
        for (int m = 0; m < 8; ++m) {
            int row = wr * 128 + m * 16 + lane15;
            bm[m] = fmaxf(fmaxf(fmx[row * 4], fmx[row * 4 + 1]),
                          fmaxf(fmx[row * 4 + 2], fmx[row * 4 + 3]));
        }
        float sm[8];
        #pragma unroll
        for (int m = 0; m < 8; ++m) {
            float s = 0.f;
            #pragma unroll
            for (int n = 0; n < 4; ++n)
                if (vld[n]) {
                    #pragma unroll
                    for (int j = 0; j < 4; ++j) s += __expf(acc[m][n][j] - bm[m]);
                }
            s += __shfl_xor(s, 16);
            s += __shfl_xor(s, 32);
            sm[m] = s;
        }
        if (lane < 16) {
            #pragma unroll
            for (int m = 0; m < 8; ++m)
                fsm[(wr * 128 + m * 16 + lane15) * 4 + wcol] = sm[m];
        }
        __syncthreads();
        if (t < 256) {
            float m4 = fmaxf(fmaxf(fmx[t * 4], fmx[t * 4 + 1]), fmaxf(fmx[t * 4 + 2], fmx[t * 4 + 3]));
            float s4 = fsm[t * 4] + fsm[t * 4 + 1] + fsm[t * 4 + 2] + fsm[t * 4 + 3];
            size_t idx = (size_t)(r0 + t) * nct + by;
            pmax[idx] = m4;
            psum[idx] = s4;
        }
    }

    // store bf16 as uint2 (4 consecutive cols per lane)
    #pragma unroll
    for (int m = 0; m < 8; ++m) {
        int row = r0 + wr * 128 + m * 16 + lane15;
        #pragma unroll
        for (int n = 0; n < 4; ++n) {
            if (vld[n]) {
                union { u16 u[4]; uint2 v; } pk;
                #pragma unroll
                for (int j = 0; j < 4; ++j) pk.u[j] = f2bf(acc[m][n][j]);
                *reinterpret_cast<uint2*>(&C[(size_t)row * ldc + cb[n]]) = pk.v;
            }
        }
    }
}

// ---------------- fused LSE + CE + probabilities + all JSDs (block per row) ----------------

__global__ __launch_bounds__(256) void probs_all(const u16* __restrict__ l5b, float* __restrict__ out,
                                                 const u16* __restrict__ pcat,
                                                 const float* __restrict__ pmax, const float* __restrict__ psum,
                                                 int nct, const int* __restrict__ tgt,
                                                 float* __restrict__ cerow,
                                                 float* __restrict__ j12, float* __restrict__ j23,
                                                 float* __restrict__ j34, float* __restrict__ j45) {
    __shared__ u16 P5[NC5];
    __shared__ float PC[LDP];
    __shared__ float sh[4];
    __shared__ float shls;
    int b = blockIdx.x, t = threadIdx.x;
    float* orow = out + (size_t)b * NC5;
    const u16* lrow = l5b + (size_t)b * NC5;
    const u16* prow = pcat + (size_t)b * LDP;

    // wave 0: reduce the per-coltile partials into the row LSE
    if (t < 64) {
        float pm = (t < nct) ? pmax[(size_t)b * nct + t] : -1e30f;
        float ps = (t < nct) ? psum[(size_t)b * nct + t] : 0.f;
        float gm = waveReduceMax(pm);
        float s = waveReduceSum(ps * __expf(pm - gm));
        if (t == 0) {
            float ls = gm + __logf(s);
            shls = ls;
            int tg = tgt[b];
            cerow[b] = -(bfu(lrow[tg]) - ls);
        }
    }
    // meanwhile: stage pcat row into LDS as f32
    for (int c = t; c < LDP / 8; c += 256) {
        uint4 raw = ((const uint4*)prow)[c];
        const u16* rp = (const u16*)&raw;
        #pragma unroll
        for (int k = 0; k < 8; ++k) PC[c * 8 + k] = bfu(rp[k]);
    }
    __syncthreads();
    float ls = shls;

    for (int c = t; c < NC5 / 8; c += 256) {
        uint4 raw = ((const uint4*)lrow)[c];
        const u16* rp = (const u16*)&raw;
        f32x4 p0, p1;
        #pragma unroll
        for (int k = 0; k < 4; ++k) p0[k] = __expf(bfu(rp[k]) - ls);
        #pragma unroll
        for (int k = 0; k < 4; ++k) p1[k] = __expf(bfu(rp[4 + k]) - ls);
        ((f32x4*)orow)[c * 2] = p0;
        ((f32x4*)orow)[c * 2 + 1] = p1;
        union { u16 u[8]; uint4 v; } pk;
        #pragma unroll
        for (int k = 0; k < 4; ++k) pk.u[k] = f2bf(p0[k]);
        #pragma unroll
        for (int k = 0; k < 4; ++k) pk.u[4 + k] = f2bf(p1[k]);
        ((uint4*)P5)[c] = pk.v;
    }
    __syncthreads();

    auto softmax_seg = [&](int off, int C) {
        float m = -1e30f;
        for (int c = t; c < C; c += 256) m = fmaxf(m, PC[off + c]);
        m = blockReduceMax(m, sh);
        float s = 0.f;
        for (int c = t; c < C; c += 256) { float e = __expf(PC[off + c] - m); PC[off + c] = e; s += e; }
        s = blockReduceSum(s, sh);
        float inv = 1.0f / s;
        for (int c = t; c < C; c += 256) PC[off + c] *= inv;
    };
    softmax_seg(0, NC1);
    softmax_seg(20, NC2);
    softmax_seg(120, NC3);
    softmax_seg(620, NC4);
    __syncthreads();

    {   // jsd45: agg p5 (fan 5) vs p4
        float klpm = 0.f, klqm = 0.f;
        for (int g = t; g < NC4; g += 256) {
            float qv = 0.f;
            #pragma unroll
            for (int f = 0; f < 5; ++f) qv += bfu(P5[5 * g + f]);
            float pp = PC[620 + g];
            float mm = 0.5f * (qv + pp);
            float lm = __logf(mm + 1e-8f);
            klpm += qv * (__logf(qv + 1e-8f) - lm);
            klqm += pp * (__logf(pp + 1e-8f) - lm);
        }
        float tot = blockReduceSum(0.5f * (klpm + klqm), sh);
        if (t == 0) j45[b] = tot;
    }
    auto jsd_seg = [&](int childOff, int fan, int parentOff, int nPar, float* dst) {
        float klpm = 0.f, klqm = 0.f;
        for (int g = t; g < nPar; g += 256) {
            float qv = 0.f;
            for (int f = 0; f < fan; ++f) qv += PC[childOff + g * fan + f];
            float pp = PC[parentOff + g];
            float mm = 0.5f * (qv + pp);
            float lm = __logf(mm + 1e-8f);
            klpm += qv * (__logf(qv + 1e-8f) - lm);
            klqm += pp * (__logf(pp + 1e-8f) - lm);
        }
        float tot = blockReduceSum(0.5f * (klpm + klqm), sh);
        if (t == 0) dst[b] = tot;
    };
    jsd_seg(620, 4, 120, NC3, j34);
    jsd_seg(120, 5, 20, NC2, j23);
    jsd_seg(20, 5, 0, NC1, j12);
}

// ---------------- weight cosine terms (all 4 levels in one launch) ----------------

__global__ __launch_bounds__(64) void wcos_all(const float* __restrict__ W1, const float* __restrict__ W2,
                                               const float* __restrict__ W3, const float* __restrict__ W4,
                                               const float* __restrict__ W5,
                                               float* __restrict__ c45, float* __restrict__ c34,
                                               float* __restrict__ c23, float* __restrict__ c12) {
    int g = blockIdx.x; int t = threadIdx.x;
    const float* Wp; const float* Wc; int fan; float* dst; int j;
    if      (g < 2000) { Wp = W4; Wc = W5; fan = 5; dst = c45; j = g; }
    else if (g < 2500) { Wp = W3; Wc = W4; fan = 4; dst = c34; j = g - 2000; }
    else if (g < 2600) { Wp = W2; Wc = W3; fan = 5; dst = c23; j = g - 2500; }
    else               { Wp = W1; Wc = W2; fan = 5; dst = c12; j = g - 2600; }

    float hat[8] = {0, 0, 0, 0, 0, 0, 0, 0};
    for (int c = 0; c < fan; ++c) {
        const float* cr = Wc + ((size_t)(j * fan + c)) * FEAT + t * 8;
        float v[8]; float ss = 0.f;
        #pragma unroll
        for (int i = 0; i < 8; ++i) { v[i] = cr[i]; ss += v[i] * v[i]; }
        ss = waveReduceSum(ss);
        float inv = 1.0f / fmaxf(sqrtf(ss), 1e-12f);
        #pragma unroll
        for (int i = 0; i < 8; ++i) hat[i] += v[i] * inv;
    }
    float hs = 0.f;
    #pragma unroll
    for (int i = 0; i < 8; ++i) hs += hat[i] * hat[i];
    hs = waveReduceSum(hs);
    float hinv = 1.0f / fmaxf(sqrtf(hs), 1e-12f);
    const float* pr = Wp + (size_t)j * FEAT + t * 8;
    float ps = 0.f, dot = 0.f;
    #pragma unroll
    for (int i = 0; i < 8; ++i) { float pv = pr[i]; ps += pv * pv; dot += pv * hat[i]; }
    ps = waveReduceSum(ps);
    dot = waveReduceSum(dot);
    if (t == 0) dst[j] = dot * hinv / fmaxf(sqrtf(ps), 1e-12f);
}

__global__ __launch_bounds__(256) void finalize(const float* __restrict__ ce, const float* __restrict__ j45,
                                                const float* __restrict__ j34, const float* __restrict__ j23,
                                                const float* __restrict__ j12, const float* __restrict__ c45,
                                                const float* __restrict__ c34, const float* __restrict__ c23,
                                                const float* __restrict__ c12, float* __restrict__ lossOut) {
    __shared__ float sh[4];
    auto meanArr = [&](const float* a, int n) {
        float s = 0.f;
        for (int i = threadIdx.x; i < n; i += 256) s += a[i];
        s = blockReduceSum(s, sh);
        return s / n;
    };
    float loss = meanArr(ce, BATCH);
    loss += meanArr(j45, BATCH) + meanArr(j34, BATCH) + meanArr(j23, BATCH) + meanArr(j12, BATCH);
    loss -= meanArr(c45, NC4) + meanArr(c34, NC3) + meanArr(c23, NC2) + meanArr(c12, NC1);
    if (threadIdx.x == 0) *lossOut = loss;
}

// ---------------- launch ----------------

extern "C" void kernel_launch(void* const* d_in, const int* in_sizes, int n_in,
                              void* d_out, int out_size, void* d_ws, size_t ws_size,
                              hipStream_t stream) {
    const float* x  = (const float*)d_in[0];
    const int*   tg = (const int*)d_in[1];
    const float* W1 = (const float*)d_in[2];  const float* b1 = (const float*)d_in[3];
    const float* W2 = (const float*)d_in[4];  const float* b2 = (const float*)d_in[5];
    const float* W3 = (const float*)d_in[6];  const float* b3 = (const float*)d_in[7];
    const float* W4 = (const float*)d_in[8];  const float* b4 = (const float*)d_in[9];
    const float* W5 = (const float*)d_in[10]; const float* b5 = (const float*)d_in[11];
    float* out = (float*)d_out;

    const int NCT = (NC5 + BN - 1) / BN;   // 40 column tiles for l5

    char* ws = (char*)d_ws;
    size_t off = 0;
    auto alloc = [&](size_t bytes) { void* p = ws + off; off = (off + bytes + 255) & ~(size_t)255; return p; };
    u16*   xb      = (u16*)alloc((size_t)BATCH * FEAT * 2);
    u16*   wb      = (u16*)alloc((size_t)NTOT * FEAT * 2);
    float* biascat = (float*)alloc((size_t)NTOT * 4);
    u16*   pcat    = (u16*)alloc((size_t)BATCH * LDP * 2);
    u16*   l5b     = (u16*)alloc((size_t)BATCH * NC5 * 2);
    float* pmax    = (float*)alloc((size_t)BATCH * NCT * 4);
    float* psum    = (float*)alloc((size_t)BATCH * NCT * 4);
    float* cerow   = (float*)alloc((size_t)BATCH * 4);
    float* j45     = (float*)alloc((size_t)BATCH * 4);
    float* j34     = (float*)alloc((size_t)BATCH * 4);
    float* j23     = (float*)alloc((size_t)BATCH * 4);
    float* j12     = (float*)alloc((size_t)BATCH * 4);
    float* c45     = (float*)alloc((size_t)NC4 * 4);
    float* c34     = (float*)alloc((size_t)NC3 * 4);
    float* c23     = (float*)alloc((size_t)NC2 * 4);
    float* c12     = (float*)alloc((size_t)NC1 * 4);

    cast_x<<<(BATCH * FEAT / 8 + 255) / 256, 256, 0, stream>>>(x, xb, BATCH * FEAT / 8);
    wnorm_all<<<NTOT, 64, 0, stream>>>(W1, b1, W2, b2, W3, b3, W4, b4, W5, b5, wb, biascat);

    gemm_bt<false><<<dim3(BATCH / BM, (NCAT + BN - 1) / BN), 512, 0, stream>>>(
        xb, wb, biascat, pcat, NCAT, LDP, nullptr, nullptr, 0);
    gemm_bt<true><<<dim3(BATCH / BM, NCT), 512, 0, stream>>>(
        xb, wb + (size_t)NCAT * FEAT, biascat + NCAT, l5b, NC5, NC5, pmax, psum, NCT);

    probs_all<<<BATCH, 256, 0, stream>>>(l5b, out, pcat, pmax, psum, NCT, tg, cerow,
                                         j12, j23, j34, j45);

    wcos_all<<<NC4 + NC3 + NC2 + NC1, 64, 0, stream>>>(W1, W2, W3, W4, W5, c45, c34, c23, c12);

    finalize<<<1, 256, 0, stream>>>(cerow, j45, j34, j23, j12, c45, c34, c23, c12,
                                    out + (size_t)BATCH * NC5);
}

// Round 7
// 391.860 us; speedup vs baseline: 1.9512x; 1.0589x over previous
//
#include <hip/hip_runtime.h>
#include <hip/hip_bf16.h>
#include <stdint.h>

typedef unsigned short u16;
typedef __bf16 bf16x8 __attribute__((ext_vector_type(8)));
typedef float f32x4 __attribute__((ext_vector_type(4)));
typedef unsigned int u32x4 __attribute__((ext_vector_type(4)));

#define FEAT 512
#define BATCH 8192
#define NC1 20
#define NC2 100
#define NC3 500
#define NC4 2000
#define NC5 10000
#define NCAT 2620
#define LDP 2624          // padded leading dim for pcat (16B-clean bf16 rows)
#define NTOT 12620
#define WN_BLOCKS 3155    // ceil(12620 / 4) wnorm blocks (4 rows x 64 lanes)
#define CAST_BLOCKS 2048  // 8192*512/8/256

__device__ inline u16 f2bf(float f) {
    unsigned int u = __builtin_bit_cast(unsigned int, f);
    unsigned int r = (u + 0x7FFFu + ((u >> 16) & 1u)) >> 16;
    return (u16)r;
}
__device__ inline float bfu(u16 u) {
    return __builtin_bit_cast(float, (unsigned int)u << 16);
}

__device__ inline float waveReduceSum(float v) {
    #pragma unroll
    for (int off = 32; off > 0; off >>= 1) v += __shfl_xor(v, off);
    return v;
}
__device__ inline float waveReduceMax(float v) {
    #pragma unroll
    for (int off = 32; off > 0; off >>= 1) v = fmaxf(v, __shfl_xor(v, off));
    return v;
}
__device__ inline float blockReduceSum(float v, float* sh) {
    int t = threadIdx.x;
    v = waveReduceSum(v);
    __syncthreads();
    if ((t & 63) == 0) sh[t >> 6] = v;
    __syncthreads();
    return sh[0] + sh[1] + sh[2] + sh[3];
}
__device__ inline float blockReduceMax(float v, float* sh) {
    int t = threadIdx.x;
    v = waveReduceMax(v);
    __syncthreads();
    if ((t & 63) == 0) sh[t >> 6] = v;
    __syncthreads();
    return fmaxf(fmaxf(sh[0], sh[1]), fmaxf(sh[2], sh[3]));
}

__device__ inline void gload16(const void* g, void* l) {
    __builtin_amdgcn_global_load_lds((const __attribute__((address_space(1))) void*)g,
                                     (__attribute__((address_space(3))) void*)l, 16, 0, 0);
}

// ---------------- prep: cast x to bf16 + l2-normalize all weights ----------------

__global__ __launch_bounds__(256) void prep(const float* __restrict__ x, u16* __restrict__ xb,
                                            const float* __restrict__ W1, const float* __restrict__ b1,
                                            const float* __restrict__ W2, const float* __restrict__ b2,
                                            const float* __restrict__ W3, const float* __restrict__ b3,
                                            const float* __restrict__ W4, const float* __restrict__ b4,
                                            const float* __restrict__ W5, const float* __restrict__ b5,
                                            u16* __restrict__ wb, float* __restrict__ biascat) {
    int bid = blockIdx.x;
    if (bid < WN_BLOCKS) {
        int r = bid * 4 + (threadIdx.x >> 6);
        if (r >= NTOT) return;
        int t = threadIdx.x & 63;
        const float* W; const float* b; int lr;
        if      (r < 20)   { W = W1; b = b1; lr = r; }
        else if (r < 120)  { W = W2; b = b2; lr = r - 20; }
        else if (r < 620)  { W = W3; b = b3; lr = r - 120; }
        else if (r < 2620) { W = W4; b = b4; lr = r - 620; }
        else               { W = W5; b = b5; lr = r - 2620; }
        const float* p = W + (size_t)lr * FEAT + t * 8;
        float v[8]; float ss = 0.f;
        #pragma unroll
        for (int j = 0; j < 8; ++j) { v[j] = p[j]; ss += v[j] * v[j]; }
        ss = waveReduceSum(ss);
        float inv = 1.0f / fmaxf(sqrtf(ss), 1e-12f);
        union { u16 u[8]; uint4 q; } o;
        #pragma unroll
        for (int j = 0; j < 8; ++j) o.u[j] = f2bf(v[j] * inv);
        ((uint4*)(wb + (size_t)r * FEAT))[t] = o.q;
        if (t == 0) biascat[r] = b[lr];
    } else {
        int i = (bid - WN_BLOCKS) * 256 + threadIdx.x;
        const float* p = x + (size_t)i * 8;
        union { u16 u[8]; uint4 v; } o;
        #pragma unroll
        for (int j = 0; j < 8; ++j) o.u[j] = f2bf(p[j]);
        ((uint4*)xb)[i] = o.v;
    }
}

// ---------------- GEMM over all 12620 columns ----------------
// 256x256 tile, 8 waves (2x4), BK=64, double-buffered global_load_lds w16,
// XOR-swizzled LDS, transposed mfma (lane holds 4 consecutive output cols),
// counted-vmcnt raw-barrier pipeline, setprio around MFMA cluster.
// cols < NCAT -> pcat (bf16, ld LDP); cols >= NCAT -> l5b (bf16, ld NC5)
// + per-(row, coltile) softmax partials for the l5 region (by >= 10).

#define BM 256
#define BN 256
#define BK 64
#define KITERS (FEAT / BK)

__global__ __launch_bounds__(512, 2) void gemm_all(const u16* __restrict__ A, const u16* __restrict__ Bw,
                                                   const float* __restrict__ bias,
                                                   u16* __restrict__ pcat, u16* __restrict__ l5b,
                                                   float* __restrict__ pmax, float* __restrict__ psum) {
    __shared__ u16 sAB[2][2 * BM * BK];        // 2 x 64 KB double buffer
    const int t = threadIdx.x;
    const int lane = t & 63, wid = t >> 6;
    const int lane15 = lane & 15, q = lane >> 4;
    const int wr = wid >> 2, wcol = wid & 3;

    // XCD-aware bijective swizzle (nwg = 32*50 = 1600, %8 == 0)
    int nwg = gridDim.x * gridDim.y;
    int lid = blockIdx.y * gridDim.x + blockIdx.x;
    int cpx = nwg >> 3;
    int swz = (lid & 7) * cpx + (lid >> 3);
    int bx = swz % gridDim.x, by = swz / gridDim.x;
    const int r0 = bx * BM, c0 = by * BN;

    f32x4 acc[8][4];
    #pragma unroll
    for (int m = 0; m < 8; ++m)
        #pragma unroll
        for (int n = 0; n < 4; ++n) acc[m][n] = f32x4{0.f, 0.f, 0.f, 0.f};

    auto stage = [&](int kt, int buf) {
        char* base = (char*)sAB[buf];
        #pragma unroll
        for (int p = 0; p < 8; ++p) {
            int chunk = p * 512 + t;            // 0..4095 (16B each)
            int row = chunk >> 3, blk = chunk & 7;
            int srck = 8 * (blk ^ (row & 7));   // swizzled source k (bf16 idx)
            const u16* g;
            if (p < 4) {
                g = A + (size_t)(r0 + row) * FEAT + kt + srck;
            } else {
                int brow = c0 + (row - 256); if (brow >= NTOT) brow = NTOT - 1;
                g = Bw + (size_t)brow * FEAT + kt + srck;
            }
            gload16(g, base + (size_t)chunk * 16);
        }
    };

    stage(0, 0);            // 8 loads in flight
    stage(BK, 1);           // 16 in flight
    for (int ki = 0; ki < KITERS; ++ki) {
        if (ki + 1 < KITERS) { asm volatile("s_waitcnt vmcnt(8)" ::: "memory"); }
        else                 { asm volatile("s_waitcnt vmcnt(0)" ::: "memory"); }
        __builtin_amdgcn_sched_barrier(0);
        __builtin_amdgcn_s_barrier();
        __builtin_amdgcn_sched_barrier(0);
        char* sAb = (char*)sAB[ki & 1];
        char* sBb = sAb + BM * BK * 2;
        #pragma unroll
        for (int ks = 0; ks < 2; ++ks) {
            const int kko = ks * 4 + q;
            bf16x8 af[8], bv[4];
            #pragma unroll
            for (int m = 0; m < 8; ++m) {
                int row = wr * 128 + m * 16 + lane15;
                af[m] = *reinterpret_cast<const bf16x8*>(sAb + row * 128 + 16 * (kko ^ (row & 7)));
            }
            #pragma unroll
            for (int n = 0; n < 4; ++n) {
                int row = wcol * 64 + n * 16 + lane15;
                bv[n] = *reinterpret_cast<const bf16x8*>(sBb + row * 128 + 16 * (kko ^ (row & 7)));
            }
            __builtin_amdgcn_s_setprio(1);
            #pragma unroll
            for (int m = 0; m < 8; ++m)
                #pragma unroll
                for (int n = 0; n < 4; ++n)
                    acc[m][n] = __builtin_amdgcn_mfma_f32_16x16x32_bf16(bv[n], af[m], acc[m][n], 0, 0, 0);
            __builtin_amdgcn_s_setprio(0);
        }
        __builtin_amdgcn_sched_barrier(0);
        __builtin_amdgcn_s_barrier();
        __builtin_amdgcn_sched_barrier(0);
        if (ki + 2 < KITERS) stage((ki + 2) * BK, ki & 1);
    }

    // transposed D layout: lane holds row = r0+wr*128+m*16+lane15,
    // cols cb..cb+3 with cb = c0+wcol*64+n*16+q*4 (fragment never spans
    // the pcat/l5 boundary since NCAT % 4 == 0)
    bool vld[4], svld[4]; int cb[4];
    #pragma unroll
    for (int n = 0; n < 4; ++n) {
        cb[n] = c0 + wcol * 64 + n * 16 + q * 4;
        vld[n] = (cb[n] < NTOT);
        svld[n] = vld[n] && (cb[n] >= NCAT);
        if (vld[n]) {
            float b0 = bias[cb[n]], b1 = bias[cb[n] + 1], b2 = bias[cb[n] + 2], b3 = bias[cb[n] + 3];
            #pragma unroll
            for (int m = 0; m < 8; ++m) {
                acc[m][n][0] += b0; acc[m][n][1] += b1;
                acc[m][n][2] += b2; acc[m][n][3] += b3;
            }
        }
    }

    if (by >= 10) {   // this col-tile overlaps the l5 region: emit softmax partials
        float* fmx = (float*)sAB;            // [256][4] row-max per wcol
        float* fsm = fmx + 1024;             // [256][4] row-sumexp per wcol
        float bm[8];
        #pragma unroll
        for (int m = 0; m < 8; ++m) {
            float v = -1e30f;
            #pragma unroll
            for (int n = 0; n < 4; ++n)
                if (svld[n]) {
                    #pragma unroll
                    for (int j = 0; j < 4; ++j) v = fmaxf(v, acc[m][n][j]);
                }
            v = fmaxf(v, __shfl_xor(v, 16));
            v = fmaxf(v, __shfl_xor(v, 32));
            bm[m] = v;
        }
        if (lane < 16) {
            #pragma unroll
            for (int m = 0; m < 8; ++m)
                fmx[(wr * 128 + m * 16 + lane15) * 4 + wcol] = bm[m];
        }
        __syncthreads();
        #pragma unroll
        for (int m = 0; m < 8; ++m) {
            int row = wr * 128 + m * 16 + lane15;
            bm[m] = fmaxf(fmaxf(fmx[row * 4], fmx[row * 4 + 1]),
                          fmaxf(fmx[row * 4 + 2], fmx[row * 4 + 3]));
        }
        float sm[8];
        #pragma unroll
        for (int m = 0; m < 8; ++m) {
            float s = 0.f;
            #pragma unroll
            for (int n = 0; n < 4; ++n)
                if (svld[n]) {
                    #pragma unroll
                    for (int j = 0; j < 4; ++j) s += __expf(acc[m][n][j] - bm[m]);
                }
            s += __shfl_xor(s, 16);
            s += __shfl_xor(s, 32);
            sm[m] = s;
        }
        if (lane < 16) {
            #pragma unroll
            for (int m = 0; m < 8; ++m)
                fsm[(wr * 128 + m * 16 + lane15) * 4 + wcol] = sm[m];
        }
        __syncthreads();
        if (t < 256) {
            float m4 = fmaxf(fmaxf(fmx[t * 4], fmx[t * 4 + 1]), fmaxf(fmx[t * 4 + 2], fmx[t * 4 + 3]));
            float s4 = fsm[t * 4] + fsm[t * 4 + 1] + fsm[t * 4 + 2] + fsm[t * 4 + 3];
            size_t idx = (size_t)(r0 + t) * 40 + (by - 10);
            pmax[idx] = m4;
            psum[idx] = s4;
        }
    }

    // store bf16 as uint2 (4 consecutive cols per lane), routed per region
    #pragma unroll
    for (int m = 0; m < 8; ++m) {
        int row = r0 + wr * 128 + m * 16 + lane15;
        #pragma unroll
        for (int n = 0; n < 4; ++n) {
            if (vld[n]) {
                union { u16 u[4]; uint2 v; } pk;
                #pragma unroll
                for (int j = 0; j < 4; ++j) pk.u[j] = f2bf(acc[m][n][j]);
                u16* dst = (cb[n] < NCAT)
                    ? &pcat[(size_t)row * LDP + cb[n]]
                    : &l5b[(size_t)row * NC5 + (cb[n] - NCAT)];
                *reinterpret_cast<uint2*>(dst) = pk.v;
            }
        }
    }
}

// ---------------- fused LSE + CE + probabilities + all JSDs (block per row) ----------------

__global__ __launch_bounds__(256) void probs_all(const u16* __restrict__ l5b, float* __restrict__ out,
                                                 const u16* __restrict__ pcat,
                                                 const float* __restrict__ pmax, const float* __restrict__ psum,
                                                 int nct, const int* __restrict__ tgt,
                                                 float* __restrict__ cerow,
                                                 float* __restrict__ j12, float* __restrict__ j23,
                                                 float* __restrict__ j34, float* __restrict__ j45) {
    __shared__ u16 P5[NC5];
    __shared__ float PC[LDP];
    __shared__ float sh[4];
    __shared__ float shls;
    int b = blockIdx.x, t = threadIdx.x;
    float* orow = out + (size_t)b * NC5;
    const u16* lrow = l5b + (size_t)b * NC5;
    const u16* prow = pcat + (size_t)b * LDP;

    // wave 0: reduce the per-coltile partials into the row LSE
    if (t < 64) {
        float pm = (t < nct) ? pmax[(size_t)b * nct + t] : -1e30f;
        float ps = (t < nct) ? psum[(size_t)b * nct + t] : 0.f;
        float gm = waveReduceMax(pm);
        float s = waveReduceSum(ps * __expf(pm - gm));
        if (t == 0) {
            float ls = gm + __logf(s);
            shls = ls;
            int tg = tgt[b];
            cerow[b] = -(bfu(lrow[tg]) - ls);
        }
    }
    // meanwhile: stage pcat row into LDS as f32
    for (int c = t; c < LDP / 8; c += 256) {
        u32x4 raw = __builtin_nontemporal_load(&((const u32x4*)prow)[c]);
        const u16* rp = (const u16*)&raw;
        #pragma unroll
        for (int k = 0; k < 8; ++k) PC[c * 8 + k] = bfu(rp[k]);
    }
    __syncthreads();
    float ls = shls;

    for (int c = t; c < NC5 / 8; c += 256) {
        u32x4 raw = __builtin_nontemporal_load(&((const u32x4*)lrow)[c]);
        const u16* rp = (const u16*)&raw;
        f32x4 p0, p1;
        #pragma unroll
        for (int k = 0; k < 4; ++k) p0[k] = __expf(bfu(rp[k]) - ls);
        #pragma unroll
        for (int k = 0; k < 4; ++k) p1[k] = __expf(bfu(rp[4 + k]) - ls);
        __builtin_nontemporal_store(p0, &((f32x4*)orow)[c * 2]);
        __builtin_nontemporal_store(p1, &((f32x4*)orow)[c * 2 + 1]);
        union { u16 u[8]; uint4 v; } pk;
        #pragma unroll
        for (int k = 0; k < 4; ++k) pk.u[k] = f2bf(p0[k]);
        #pragma unroll
        for (int k = 0; k < 4; ++k) pk.u[4 + k] = f2bf(p1[k]);
        ((uint4*)P5)[c] = pk.v;
    }
    __syncthreads();

    auto softmax_seg = [&](int off, int C) {
        float m = -1e30f;
        for (int c = t; c < C; c += 256) m = fmaxf(m, PC[off + c]);
        m = blockReduceMax(m, sh);
        float s = 0.f;
        for (int c = t; c < C; c += 256) { float e = __expf(PC[off + c] - m); PC[off + c] = e; s += e; }
        s = blockReduceSum(s, sh);
        float inv = 1.0f / s;
        for (int c = t; c < C; c += 256) PC[off + c] *= inv;
    };
    softmax_seg(0, NC1);
    softmax_seg(20, NC2);
    softmax_seg(120, NC3);
    softmax_seg(620, NC4);
    __syncthreads();

    {   // jsd45: agg p5 (fan 5) vs p4
        float klpm = 0.f, klqm = 0.f;
        for (int g = t; g < NC4; g += 256) {
            float qv = 0.f;
            #pragma unroll
            for (int f = 0; f < 5; ++f) qv += bfu(P5[5 * g + f]);
            float pp = PC[620 + g];
            float mm = 0.5f * (qv + pp);
            float lm = __logf(mm + 1e-8f);
            klpm += qv * (__logf(qv + 1e-8f) - lm);
            klqm += pp * (__logf(pp + 1e-8f) - lm);
        }
        float tot = blockReduceSum(0.5f * (klpm + klqm), sh);
        if (t == 0) j45[b] = tot;
    }
    auto jsd_seg = [&](int childOff, int fan, int parentOff, int nPar, float* dst) {
        float klpm = 0.f, klqm = 0.f;
        for (int g = t; g < nPar; g += 256) {
            float qv = 0.f;
            for (int f = 0; f < fan; ++f) qv += PC[childOff + g * fan + f];
            float pp = PC[parentOff + g];
            float mm = 0.5f * (qv + pp);
            float lm = __logf(mm + 1e-8f);
            klpm += qv * (__logf(qv + 1e-8f) - lm);
            klqm += pp * (__logf(pp + 1e-8f) - lm);
        }
        float tot = blockReduceSum(0.5f * (klpm + klqm), sh);
        if (t == 0) dst[b] = tot;
    };
    jsd_seg(620, 4, 120, NC3, j34);
    jsd_seg(120, 5, 20, NC2, j23);
    jsd_seg(20, 5, 0, NC1, j12);
}

// ---------------- weight cosine terms (from normalized bf16 wb) ----------------
// child rows of wb are unit-norm already -> hat = sum of child rows; parent
// rows are unit-norm -> cos = dot(parent, hat)/|hat|.

__global__ __launch_bounds__(64) void wcos_all(const u16* __restrict__ wb,
                                               float* __restrict__ c45, float* __restrict__ c34,
                                               float* __restrict__ c23, float* __restrict__ c12) {
    int g = blockIdx.x; int t = threadIdx.x;
    int pOff, cOff, fan, j; float* dst;
    if      (g < 2000) { pOff = 620; cOff = 2620; fan = 5; dst = c45; j = g; }
    else if (g < 2500) { pOff = 120; cOff = 620;  fan = 4; dst = c34; j = g - 2000; }
    else if (g < 2600) { pOff = 20;  cOff = 120;  fan = 5; dst = c23; j = g - 2500; }
    else               { pOff = 0;   cOff = 20;   fan = 5; dst = c12; j = g - 2600; }

    float hat[8] = {0, 0, 0, 0, 0, 0, 0, 0};
    for (int c = 0; c < fan; ++c) {
        const uint4 raw = ((const uint4*)(wb + (size_t)(cOff + j * fan + c) * FEAT))[t];
        const u16* rp = (const u16*)&raw;
        #pragma unroll
        for (int i = 0; i < 8; ++i) hat[i] += bfu(rp[i]);
    }
    float hs = 0.f;
    #pragma unroll
    for (int i = 0; i < 8; ++i) hs += hat[i] * hat[i];
    hs = waveReduceSum(hs);
    float hinv = 1.0f / fmaxf(sqrtf(hs), 1e-12f);
    const uint4 praw = ((const uint4*)(wb + (size_t)(pOff + j) * FEAT))[t];
    const u16* pp = (const u16*)&praw;
    float dot = 0.f;
    #pragma unroll
    for (int i = 0; i < 8; ++i) dot += bfu(pp[i]) * hat[i];
    dot = waveReduceSum(dot);
    if (t == 0) dst[j] = dot * hinv;
}

__global__ __launch_bounds__(256) void finalize(const float* __restrict__ ce, const float* __restrict__ j45,
                                                const float* __restrict__ j34, const float* __restrict__ j23,
                                                const float* __restrict__ j12, const float* __restrict__ c45,
                                                const float* __restrict__ c34, const float* __restrict__ c23,
                                                const float* __restrict__ c12, float* __restrict__ lossOut) {
    __shared__ float sh[4];
    auto meanArr = [&](const float* a, int n) {
        float s = 0.f;
        for (int i = threadIdx.x; i < n; i += 256) s += a[i];
        s = blockReduceSum(s, sh);
        return s / n;
    };
    float loss = meanArr(ce, BATCH);
    loss += meanArr(j45, BATCH) + meanArr(j34, BATCH) + meanArr(j23, BATCH) + meanArr(j12, BATCH);
    loss -= meanArr(c45, NC4) + meanArr(c34, NC3) + meanArr(c23, NC2) + meanArr(c12, NC1);
    if (threadIdx.x == 0) *lossOut = loss;
}

// ---------------- launch ----------------

extern "C" void kernel_launch(void* const* d_in, const int* in_sizes, int n_in,
                              void* d_out, int out_size, void* d_ws, size_t ws_size,
                              hipStream_t stream) {
    const float* x  = (const float*)d_in[0];
    const int*   tg = (const int*)d_in[1];
    const float* W1 = (const float*)d_in[2];  const float* b1 = (const float*)d_in[3];
    const float* W2 = (const float*)d_in[4];  const float* b2 = (const float*)d_in[5];
    const float* W3 = (const float*)d_in[6];  const float* b3 = (const float*)d_in[7];
    const float* W4 = (const float*)d_in[8];  const float* b4 = (const float*)d_in[9];
    const float* W5 = (const float*)d_in[10]; const float* b5 = (const float*)d_in[11];
    float* out = (float*)d_out;

    const int NCT = 40;   // l5 column tiles (by = 10..49)

    char* ws = (char*)d_ws;
    size_t off = 0;
    auto alloc = [&](size_t bytes) { void* p = ws + off; off = (off + bytes + 255) & ~(size_t)255; return p; };
    u16*   xb      = (u16*)alloc((size_t)BATCH * FEAT * 2);
    u16*   wb      = (u16*)alloc((size_t)NTOT * FEAT * 2);
    float* biascat = (float*)alloc((size_t)NTOT * 4);
    u16*   pcat    = (u16*)alloc((size_t)BATCH * LDP * 2);
    u16*   l5b     = (u16*)alloc((size_t)BATCH * NC5 * 2);
    float* pmax    = (float*)alloc((size_t)BATCH * NCT * 4);
    float* psum    = (float*)alloc((size_t)BATCH * NCT * 4);
    float* cerow   = (float*)alloc((size_t)BATCH * 4);
    float* j45     = (float*)alloc((size_t)BATCH * 4);
    float* j34     = (float*)alloc((size_t)BATCH * 4);
    float* j23     = (float*)alloc((size_t)BATCH * 4);
    float* j12     = (float*)alloc((size_t)BATCH * 4);
    float* c45     = (float*)alloc((size_t)NC4 * 4);
    float* c34     = (float*)alloc((size_t)NC3 * 4);
    float* c23     = (float*)alloc((size_t)NC2 * 4);
    float* c12     = (float*)alloc((size_t)NC1 * 4);

    prep<<<WN_BLOCKS + CAST_BLOCKS, 256, 0, stream>>>(x, xb, W1, b1, W2, b2, W3, b3, W4, b4, W5, b5,
                                                      wb, biascat);

    gemm_all<<<dim3(BATCH / BM, (NTOT + BN - 1) / BN), 512, 0, stream>>>(
        xb, wb, biascat, pcat, l5b, pmax, psum);

    probs_all<<<BATCH, 256, 0, stream>>>(l5b, out, pcat, pmax, psum, NCT, tg, cerow,
                                         j12, j23, j34, j45);

    wcos_all<<<NC4 + NC3 + NC2 + NC1, 64, 0, stream>>>(wb, c45, c34, c23, c12);

    finalize<<<1, 256, 0, stream>>>(cerow, j45, j34, j23, j12, c45, c34, c23, c12,
                                    out + (size_t)BATCH * NC5);
}